// Round 10
// baseline (605.462 us; speedup 1.0000x reference)
//
#include <hip/hip_runtime.h>

typedef __attribute__((ext_vector_type(4))) float f32x4;
typedef __attribute__((ext_vector_type(8))) unsigned short u16x8;

#define AS1(p) ((const __attribute__((address_space(1))) void*)(p))
#define AS3(p) ((__attribute__((address_space(3))) void*)(p))

__device__ __forceinline__ unsigned short f2bf(float f) {
  unsigned u = __builtin_bit_cast(unsigned, f);
  u += 0x7fffu + ((u >> 16) & 1u);
  return (unsigned short)(u >> 16);
}
__device__ __forceinline__ float bf2f(unsigned short s) {
  unsigned u = ((unsigned)s) << 16;
  return __builtin_bit_cast(float, u);
}
// fp32 -> OCP e4m3fn (RNE, FTZ below 2^-6, clamp 448). Error budget is ~1e-3
// relative (gamma=1e-6 scales the whole GEMM path); this is far more accurate.
__device__ __forceinline__ unsigned f2e4m3(float f) {
  unsigned uf = __builtin_bit_cast(unsigned, f);
  unsigned s = (uf >> 24) & 0x80u;
  unsigned u = uf & 0x7fffffffu;
  if (u < 0x3c800000u) return s;           // < 2^-6 -> 0
  if (u > 0x43e00000u) u = 0x43e00000u;    // clamp 448
  u += 0x7ffffu + ((u >> 20) & 1u);        // RNE to 3 mantissa bits
  unsigned v = (u >> 20) - 960u;
  if (v > 126u) v = 126u;
  return s | v;
}

// ---------------- fp32 -> fp8 cast with scale (weights x32) ----------------
__global__ __launch_bounds__(256) void cast_fp8(const float* __restrict__ in,
                                                unsigned char* __restrict__ out,
                                                long n, float scale) {
  long i = ((long)blockIdx.x * 256 + threadIdx.x) * 4;
  long stride = (long)gridDim.x * 256 * 4;
  for (; i < n; i += stride) {
    float4 f = *(const float4*)(in + i);
    unsigned v = f2e4m3(f.x * scale) | (f2e4m3(f.y * scale) << 8) |
                 (f2e4m3(f.z * scale) << 16) | (f2e4m3(f.w * scale) << 24);
    *(unsigned*)(out + i) = v;
  }
}

// ---------------- hierarchical column cummax scan ----------------
__global__ __launch_bounds__(256) void scan_chunkmax(const float* __restrict__ x,
                                                     float* __restrict__ partial) {
  int col = blockIdx.x * 256 + threadIdx.x;
  int chunk = blockIdx.y;
  const float* p = x + (long)chunk * 64 * 1024 + col;
  float m = -INFINITY;
#pragma unroll 4
  for (int i = 0; i < 64; i++) m = fmaxf(m, p[(long)i * 1024]);
  partial[chunk * 1024 + col] = m;
}

__global__ __launch_bounds__(256) void scan_chunkscan(const float* __restrict__ partial,
                                                      float* __restrict__ prefix,
                                                      float* __restrict__ suffix) {
  int col = blockIdx.x * 256 + threadIdx.x;
  float run = -INFINITY;
  for (int c = 0; c < 128; c++) {
    prefix[c * 1024 + col] = run;
    run = fmaxf(run, partial[c * 1024 + col]);
  }
  run = -INFINITY;
  for (int c = 127; c >= 0; c--) {
    suffix[c * 1024 + col] = run;
    run = fmaxf(run, partial[c * 1024 + col]);
  }
}

// Emits h_in FP8 [8192, 3072]: x | before | after
__global__ __launch_bounds__(256) void scan_emit(const float* __restrict__ x,
                                                 const float* __restrict__ prefix,
                                                 const float* __restrict__ suffix,
                                                 unsigned char* __restrict__ h_in) {
  int col = blockIdx.x * 256 + threadIdx.x;
  int chunk = blockIdx.y;
  long r0 = (long)chunk * 64;
  float run = prefix[chunk * 1024 + col];
  for (int i = 0; i < 64; i++) {
    long row = r0 + i;
    float v = x[row * 1024 + col];
    unsigned char* hr = h_in + row * 3072;
    hr[col] = (unsigned char)f2e4m3(v);
    hr[1024 + col] = (unsigned char)(row == 0 ? 0u : f2e4m3(run));
    run = fmaxf(run, v);
  }
  float run2 = suffix[chunk * 1024 + col];
  for (int i = 63; i >= 0; i--) {
    long row = r0 + i;
    float v = x[row * 1024 + col];
    h_in[row * 3072 + 2048 + col] = (unsigned char)(row == 8191 ? 0u : f2e4m3(run2));
    run2 = fmaxf(run2, v);
  }
}

// ============ 256x256 FP8 GEMM (r8 schedule): h_act = relu(A@B^T * 1/32 + bias) bf16 ============
// A [M,K]=h_in fp8, B [N,K]=W1q fp8 (x32). BK=64 (64B rows). 8 waves 2Mx4N.
// LDS: A 3x16K @0/16/32K, B 2x16K @48K/64K = 80KB -> 2 blocks/CU (lockstep broken).
// 64B rows + b64 frag reads: near-conflict-free linear layout, NO swizzle needed.
// Stages 4/group (p0/p1: A(g+2) h0/h1; p2/p3: B(g+2) h0/h1); vmcnt(3) at p2.
__global__ __launch_bounds__(512, 2) void gemm256_relu(
    const unsigned char* __restrict__ A, const unsigned char* __restrict__ B,
    unsigned short* __restrict__ C, const float* __restrict__ bias,
    int M, int N, int K) {
  extern __shared__ char smem[];
  const int NT = K >> 6;

  const int nwg = gridDim.x;
  const int cpx = nwg >> 3;
  const int bid = blockIdx.x;
  const int swz = (bid & 7) * cpx + (bid >> 3);
  const int tiles_m = M >> 8;
  const int tm = swz % tiles_m;
  const int tn = swz / tiles_m;
  const long brow = (long)tm * 256;
  const long bcol = (long)tn * 256;

  const int t = threadIdx.x;
  const int lane = t & 63, wv = t >> 6;
  const int wr = wv >> 2, wc = wv & 3;
  const int fr = lane & 15, fk = lane >> 4;

  const int srow = t >> 2;           // 0..127 (h adds 128)
  const int scol = (t & 3) * 16;     // byte col in 64B row
  const unsigned char* Asrc = A + (brow + srow) * (long)K + scol;
  const unsigned char* Bsrc = B + (bcol + srow) * (long)K + scol;
  const long hstep = (long)128 * K;

#define STAGE_A(j, reg, h)                                                     \
  __builtin_amdgcn_global_load_lds(AS1(Asrc + (h)*hstep + (j)*64),             \
      AS3(smem + (reg)*16384 + (h)*8192 + t * 16), 16, 0, 0)
#define STAGE_B(j, h)                                                          \
  __builtin_amdgcn_global_load_lds(AS1(Bsrc + (h)*hstep + (j)*64),             \
      AS3(smem + 49152 + ((j)&1) * 16384 + (h)*8192 + t * 16), 16, 0, 0)

  const char* ArdRow = smem + (wr * 128 + fr) * 64;
  const char* BrdRow = smem + 49152 + (wc * 64 + fr) * 64;
#define RD_A(ar_, m, kk) \
  (*(const long*)(ArdRow + (ar_)*16384 + (m)*1024 + (kk)*32 + fk * 8))
#define RD_B(pb_, n, kk) \
  (*(const long*)(BrdRow + (pb_)*16384 + (n)*1024 + (kk)*32 + fk * 8))

#define MFMA_PAIR(mi, a_)                                                      \
  _Pragma("unroll")                                                            \
  for (int n = 0; n < 4; ++n) {                                                \
    acc[(mi)][n] = __builtin_amdgcn_mfma_f32_16x16x32_fp8_fp8(                 \
        a_[0], bfr[n][0], acc[(mi)][n], 0, 0, 0);                              \
    acc[(mi)][n] = __builtin_amdgcn_mfma_f32_16x16x32_fp8_fp8(                 \
        a_[1], bfr[n][1], acc[(mi)][n], 0, 0, 0);                              \
  }

  f32x4 acc[8][4];
#pragma unroll
  for (int m = 0; m < 8; m++)
#pragma unroll
    for (int n = 0; n < 4; n++) acc[m][n] = (f32x4)0.f;

  // prologue: tile0 (A,B), tile1 (A,B) = 8 loads; vmcnt(4) lands tile0
  STAGE_A(0, 0, 0); STAGE_A(0, 0, 1); STAGE_B(0, 0); STAGE_B(0, 1);
  STAGE_A(1, 1, 0); STAGE_A(1, 1, 1); STAGE_B(1, 0); STAGE_B(1, 1);
  asm volatile("s_waitcnt vmcnt(4)" ::: "memory");
  __builtin_amdgcn_s_barrier();

  long bfr[4][2];
  long ap[2][2][2];  // [set][i][kk]
  ap[0][0][0] = RD_A(0, 0, 0); ap[0][0][1] = RD_A(0, 0, 1);
  ap[0][1][0] = RD_A(0, 1, 0); ap[0][1][1] = RD_A(0, 1, 1);

  int ar = 0;
  for (int g = 0; g < NT; ++g) {
    const int pb = g & 1;
    int sr = ar + 2; if (sr >= 3) sr -= 3;
    int nar = ar + 1; if (nar >= 3) nar = 0;
    const bool st = (g + 2 < NT);
#pragma unroll
    for (int p = 0; p < 4; ++p) {
      const int cs = p & 1, ns = cs ^ 1;
      if (p == 0) {
#pragma unroll
        for (int n = 0; n < 4; ++n) {
          bfr[n][0] = RD_B(pb, n, 0);
          bfr[n][1] = RD_B(pb, n, 1);
        }
      }
      asm volatile("s_waitcnt lgkmcnt(0)" ::: "memory");
      __builtin_amdgcn_sched_barrier(0);
      __builtin_amdgcn_s_setprio(1);
      MFMA_PAIR(2 * p, ap[cs][0])
      MFMA_PAIR(2 * p + 1, ap[cs][1])
      __builtin_amdgcn_s_setprio(0);
      if (p < 3) {
        ap[ns][0][0] = RD_A(ar, 2 * p + 2, 0); ap[ns][0][1] = RD_A(ar, 2 * p + 2, 1);
        ap[ns][1][0] = RD_A(ar, 2 * p + 3, 0); ap[ns][1][1] = RD_A(ar, 2 * p + 3, 1);
      } else if (g + 1 < NT) {
        ap[ns][0][0] = RD_A(nar, 0, 0); ap[ns][0][1] = RD_A(nar, 0, 1);
        ap[ns][1][0] = RD_A(nar, 1, 0); ap[ns][1][1] = RD_A(nar, 1, 1);
      }
      if (st) {
        if (p == 0) STAGE_A(g + 2, sr, 0);
        if (p == 1) STAGE_A(g + 2, sr, 1);
        if (p == 2) STAGE_B(g + 2, 0);
        if (p == 3) STAGE_B(g + 2, 1);
      }
      if (p == 2 && g + 1 < NT) {
        if (st) asm volatile("s_waitcnt vmcnt(3)" ::: "memory");
        else    asm volatile("s_waitcnt vmcnt(0)" ::: "memory");
      }
      asm volatile("s_barrier" ::: "memory");
    }
    ar = nar;
  }

  float bi[4];
#pragma unroll
  for (int n = 0; n < 4; ++n) bi[n] = bias[bcol + wc * 64 + n * 16 + fr];
  const long orow = brow + wr * 128 + fk * 4;
  const long ocol = bcol + wc * 64 + fr;
#pragma unroll
  for (int m = 0; m < 8; ++m)
#pragma unroll
    for (int n = 0; n < 4; ++n)
#pragma unroll
      for (int r = 0; r < 4; ++r) {
        float v = acc[m][n][r] * 0.03125f + bi[n];
        v = v > 0.f ? v : 0.f;
        C[(orow + m * 16 + r) * (long)N + ocol + n * 16] = f2bf(v);
      }
#undef STAGE_A
#undef STAGE_B
#undef RD_A
#undef RD_B
#undef MFMA_PAIR
}

// ============ 256x128 FP8 GEMM2: out = (A@B^T * 1/32 + bias)*gamma + resid ============
// A = h_ln fp8 [8192,4096], B = W2q fp8 (x32) [1024,4096]. 8 waves 4Mx2N.
// LDS: A 3x16K @0/16/32K, B 2x8K @48K/56K = 64KB -> 2 blocks/CU.
// Stages 3/group (p0/p1: A h0/h1; p2: B); vmcnt(3) at p2. Grid 8x32=256.
__global__ __launch_bounds__(512, 2) void gemm256_g2(
    const unsigned char* __restrict__ A, const unsigned char* __restrict__ B,
    float* __restrict__ Cf, const float* __restrict__ bias,
    const float* __restrict__ gamma, const float* __restrict__ resid,
    int M, int N, int K) {
  extern __shared__ char smem[];
  const int NT = K >> 6;

  const int nwg = gridDim.x;
  const int cpx = nwg >> 3;
  const int bid = blockIdx.x;
  const int swz = (bid & 7) * cpx + (bid >> 3);
  const int tiles_m = M >> 8;
  const int tm = swz % tiles_m;
  const int tn = swz / tiles_m;
  const long brow = (long)tm * 256;
  const long bcol = (long)tn * 128;

  const int t = threadIdx.x;
  const int lane = t & 63, wv = t >> 6;
  const int wr = wv >> 1, wc = wv & 1;
  const int fr = lane & 15, fk = lane >> 4;

  const int srow = t >> 2;
  const int scol = (t & 3) * 16;
  const unsigned char* Asrc = A + (brow + srow) * (long)K + scol;
  const unsigned char* Bsrc = B + (bcol + srow) * (long)K + scol;
  const long hstep = (long)128 * K;

#define STAGE_A2(j, reg, h)                                                    \
  __builtin_amdgcn_global_load_lds(AS1(Asrc + (h)*hstep + (j)*64),             \
      AS3(smem + (reg)*16384 + (h)*8192 + t * 16), 16, 0, 0)
#define STAGE_B2(j)                                                            \
  __builtin_amdgcn_global_load_lds(AS1(Bsrc + (j)*64),                         \
      AS3(smem + 49152 + ((j)&1) * 8192 + t * 16), 16, 0, 0)

  const char* ArdRow = smem + (wr * 64 + fr) * 64;
  const char* BrdRow = smem + 49152 + (wc * 64 + fr) * 64;
#define RD_A2(ar_, m, kk) \
  (*(const long*)(ArdRow + (ar_)*16384 + (m)*1024 + (kk)*32 + fk * 8))
#define RD_B2(pb_, n, kk) \
  (*(const long*)(BrdRow + (pb_)*8192 + (n)*1024 + (kk)*32 + fk * 8))

  f32x4 acc[4][4];
#pragma unroll
  for (int m = 0; m < 4; m++)
#pragma unroll
    for (int n = 0; n < 4; n++) acc[m][n] = (f32x4)0.f;

  // prologue: A0(2), B0(1), A1(2), B1(1) = 6 loads; vmcnt(3) lands tile0
  STAGE_A2(0, 0, 0); STAGE_A2(0, 0, 1); STAGE_B2(0);
  STAGE_A2(1, 1, 0); STAGE_A2(1, 1, 1); STAGE_B2(1);
  asm volatile("s_waitcnt vmcnt(3)" ::: "memory");
  __builtin_amdgcn_s_barrier();

  long bfr[4][2];
  long ap[2][2];
  ap[0][0] = RD_A2(0, 0, 0); ap[0][1] = RD_A2(0, 0, 1);

  int ar = 0;
  for (int g = 0; g < NT; ++g) {
    const int pb = g & 1;
    int sr = ar + 2; if (sr >= 3) sr -= 3;
    int nar = ar + 1; if (nar >= 3) nar = 0;
    const bool st = (g + 2 < NT);
#pragma unroll
    for (int p = 0; p < 4; ++p) {
      const int cs = p & 1, ns = cs ^ 1;
      if (p == 0) {
#pragma unroll
        for (int n = 0; n < 4; ++n) {
          bfr[n][0] = RD_B2(pb, n, 0);
          bfr[n][1] = RD_B2(pb, n, 1);
        }
      }
      asm volatile("s_waitcnt lgkmcnt(0)" ::: "memory");
      __builtin_amdgcn_sched_barrier(0);
      __builtin_amdgcn_s_setprio(1);
#pragma unroll
      for (int n = 0; n < 4; ++n) {
        acc[p][n] = __builtin_amdgcn_mfma_f32_16x16x32_fp8_fp8(
            ap[cs][0], bfr[n][0], acc[p][n], 0, 0, 0);
        acc[p][n] = __builtin_amdgcn_mfma_f32_16x16x32_fp8_fp8(
            ap[cs][1], bfr[n][1], acc[p][n], 0, 0, 0);
      }
      __builtin_amdgcn_s_setprio(0);
      if (p < 3) {
        ap[ns][0] = RD_A2(ar, p + 1, 0); ap[ns][1] = RD_A2(ar, p + 1, 1);
      } else if (g + 1 < NT) {
        ap[ns][0] = RD_A2(nar, 0, 0); ap[ns][1] = RD_A2(nar, 0, 1);
      }
      if (st) {
        if (p == 0) STAGE_A2(g + 2, sr, 0);
        if (p == 1) STAGE_A2(g + 2, sr, 1);
        if (p == 2) STAGE_B2(g + 2);
      }
      if (p == 2 && g + 1 < NT) {
        if (st) asm volatile("s_waitcnt vmcnt(3)" ::: "memory");
        else    asm volatile("s_waitcnt vmcnt(0)" ::: "memory");
      }
      asm volatile("s_barrier" ::: "memory");
    }
    ar = nar;
  }

  float bi[4], ga[4];
#pragma unroll
  for (int n = 0; n < 4; ++n) {
    const long col = bcol + wc * 64 + n * 16 + fr;
    bi[n] = bias[col];
    ga[n] = gamma[col];
  }
  const long orow = brow + wr * 64 + fk * 4;
  const long ocol = bcol + wc * 64 + fr;
#pragma unroll
  for (int m = 0; m < 4; ++m)
#pragma unroll
    for (int n = 0; n < 4; ++n)
#pragma unroll
      for (int r = 0; r < 4; ++r) {
        const long row = orow + m * 16 + r;
        const long col = ocol + n * 16;
        Cf[row * (long)N + col] =
            (acc[m][n][r] * 0.03125f + bi[n]) * ga[n] + resid[row * (long)N + col];
      }
#undef STAGE_A2
#undef STAGE_B2
#undef RD_A2
#undef RD_B2
}

// ---------------- LayerNorm: reads bf16 h_act, writes FP8 h_ln ----------------
__global__ __launch_bounds__(256) void ln_fp8(const unsigned short* __restrict__ h,
                                              unsigned char* __restrict__ hq,
                                              const float* __restrict__ w,
                                              const float* __restrict__ b) {
  const unsigned short* hp = h + (long)blockIdx.x * 4096;
  const int tid = threadIdx.x;
  u16x8 a0 = ((const u16x8*)hp)[tid * 2];
  u16x8 a1 = ((const u16x8*)hp)[tid * 2 + 1];
  float v[16];
#pragma unroll
  for (int j = 0; j < 8; j++) { v[j] = bf2f(a0[j]); v[8 + j] = bf2f(a1[j]); }
  float s = 0.f, q = 0.f;
#pragma unroll
  for (int j = 0; j < 16; j++) { s += v[j]; q += v[j] * v[j]; }
#pragma unroll
  for (int off = 32; off; off >>= 1) {
    s += __shfl_xor(s, off, 64);
    q += __shfl_xor(q, off, 64);
  }
  __shared__ float ss[4], sq[4];
  const int wv = tid >> 6;
  if ((tid & 63) == 0) { ss[wv] = s; sq[wv] = q; }
  __syncthreads();
  s = ss[0] + ss[1] + ss[2] + ss[3];
  q = sq[0] + sq[1] + sq[2] + sq[3];
  const float mu = s * (1.f / 4096.f);
  const float var = q * (1.f / 4096.f) - mu * mu;
  const float rs = rsqrtf(var + 1e-6f);
  unsigned o[4] = {0, 0, 0, 0};
#pragma unroll
  for (int j = 0; j < 8; j++) {
    int c0 = tid * 16 + j, c1 = c0 + 8;
    float y0 = (v[j] - mu) * rs * w[c0] + b[c0];
    float y1 = (v[8 + j] - mu) * rs * w[c1] + b[c1];
    o[j >> 2] |= f2e4m3(y0) << ((j & 3) * 8);
    o[2 + (j >> 2)] |= f2e4m3(y1) << ((j & 3) * 8);
  }
  uint4 pk = {o[0], o[1], o[2], o[3]};
  *(uint4*)(hq + (long)blockIdx.x * 4096 + tid * 16) = pk;
}

extern "C" void kernel_launch(void* const* d_in, const int* in_sizes, int n_in,
                              void* d_out, int out_size, void* d_ws, size_t ws_size,
                              hipStream_t stream) {
  const float* x     = (const float*)d_in[0];
  const float* W1    = (const float*)d_in[1];
  const float* b1    = (const float*)d_in[2];
  const float* ln_w  = (const float*)d_in[3];
  const float* ln_b  = (const float*)d_in[4];
  const float* W2    = (const float*)d_in[5];
  const float* b2    = (const float*)d_in[6];
  const float* gamma = (const float*)d_in[7];
  float* out = (float*)d_out;

  const int Nr = 8192, DIM = 1024, DFF = 4096, K1 = 3072;

  // workspace (bytes): W1q 12.58M | W2q 4.19M | h_in 25.2M | h_act bf16 67.1M |
  //                    h_ln 33.6M | partial/prefix/suffix 1.5M  (~144 MB)
  unsigned char* W1q  = (unsigned char*)d_ws;
  unsigned char* W2q  = W1q + (long)DFF * K1;
  unsigned char* h_in = W2q + (long)DIM * DFF;
  unsigned short* h_act = (unsigned short*)(h_in + (long)Nr * K1);
  unsigned char* h_ln = (unsigned char*)(h_act + (long)Nr * DFF);
  float* partial = (float*)(h_ln + (long)Nr * DFF);
  float* prefix  = partial + 128 * 1024;
  float* suffix  = prefix + 128 * 1024;

  hipFuncSetAttribute((const void*)gemm256_relu,
                      hipFuncAttributeMaxDynamicSharedMemorySize, 81920);
  hipFuncSetAttribute((const void*)gemm256_g2,
                      hipFuncAttributeMaxDynamicSharedMemorySize, 65536);

  cast_fp8<<<2048, 256, 0, stream>>>(W1, W1q, (long)DFF * K1, 32.f);
  cast_fp8<<<1024, 256, 0, stream>>>(W2, W2q, (long)DIM * DFF, 32.f);

  scan_chunkmax<<<dim3(4, 128), 256, 0, stream>>>(x, partial);
  scan_chunkscan<<<4, 256, 0, stream>>>(partial, prefix, suffix);
  scan_emit<<<dim3(4, 128), 256, 0, stream>>>(x, prefix, suffix, h_in);

  // GEMM1: h_act = relu(h_in @ W1q^T / 32 + b1)  — fp8, 80KB LDS, 2 blocks/CU
  gemm256_relu<<<512, 512, 81920, stream>>>(h_in, W1q, h_act, b1, Nr, DFF, K1);

  ln_fp8<<<Nr, 256, 0, stream>>>(h_act, h_ln, ln_w, ln_b);

  // GEMM2: out = (h_ln @ W2q^T / 32 + b2) * gamma + x  — fp8, 64KB LDS
  gemm256_g2<<<256, 512, 65536, stream>>>(h_ln, W2q, out, b2, gamma, x,
                                          Nr, DIM, DFF);
}

// Round 11
// 443.894 us; speedup vs baseline: 1.3640x; 1.3640x over previous
//
#include <hip/hip_runtime.h>

typedef __attribute__((ext_vector_type(4))) float f32x4;
typedef __attribute__((ext_vector_type(8))) unsigned short u16x8;

#define AS1(p) ((const __attribute__((address_space(1))) void*)(p))
#define AS3(p) ((__attribute__((address_space(3))) void*)(p))

__device__ __forceinline__ unsigned short f2bf(float f) {
  unsigned u = __builtin_bit_cast(unsigned, f);
  u += 0x7fffu + ((u >> 16) & 1u);
  return (unsigned short)(u >> 16);
}
__device__ __forceinline__ float bf2f(unsigned short s) {
  unsigned u = ((unsigned)s) << 16;
  return __builtin_bit_cast(float, u);
}
// fp32 -> OCP e4m3fn (RNE, FTZ below 2^-6, clamp 448)
__device__ __forceinline__ unsigned f2e4m3(float f) {
  unsigned uf = __builtin_bit_cast(unsigned, f);
  unsigned s = (uf >> 24) & 0x80u;
  unsigned u = uf & 0x7fffffffu;
  if (u < 0x3c800000u) return s;
  if (u > 0x43e00000u) u = 0x43e00000u;
  u += 0x7ffffu + ((u >> 20) & 1u);
  unsigned v = (u >> 20) - 960u;
  if (v > 126u) v = 126u;
  return s | v;
}

// ---------------- fp32 -> fp8 cast with scale (weights x32) ----------------
__global__ __launch_bounds__(256) void cast_fp8(const float* __restrict__ in,
                                                unsigned char* __restrict__ out,
                                                long n, float scale) {
  long i = ((long)blockIdx.x * 256 + threadIdx.x) * 4;
  long stride = (long)gridDim.x * 256 * 4;
  for (; i < n; i += stride) {
    float4 f = *(const float4*)(in + i);
    unsigned v = f2e4m3(f.x * scale) | (f2e4m3(f.y * scale) << 8) |
                 (f2e4m3(f.z * scale) << 16) | (f2e4m3(f.w * scale) << 24);
    *(unsigned*)(out + i) = v;
  }
}

// ---------------- hierarchical column cummax scan ----------------
__global__ __launch_bounds__(256) void scan_chunkmax(const float* __restrict__ x,
                                                     float* __restrict__ partial) {
  int col = blockIdx.x * 256 + threadIdx.x;
  int chunk = blockIdx.y;
  const float* p = x + (long)chunk * 64 * 1024 + col;
  float m = -INFINITY;
#pragma unroll 4
  for (int i = 0; i < 64; i++) m = fmaxf(m, p[(long)i * 1024]);
  partial[chunk * 1024 + col] = m;
}

__global__ __launch_bounds__(256) void scan_chunkscan(const float* __restrict__ partial,
                                                      float* __restrict__ prefix,
                                                      float* __restrict__ suffix) {
  int col = blockIdx.x * 256 + threadIdx.x;
  float run = -INFINITY;
  for (int c = 0; c < 128; c++) {
    prefix[c * 1024 + col] = run;
    run = fmaxf(run, partial[c * 1024 + col]);
  }
  run = -INFINITY;
  for (int c = 127; c >= 0; c--) {
    suffix[c * 1024 + col] = run;
    run = fmaxf(run, partial[c * 1024 + col]);
  }
}

__global__ __launch_bounds__(256) void scan_emit(const float* __restrict__ x,
                                                 const float* __restrict__ prefix,
                                                 const float* __restrict__ suffix,
                                                 unsigned char* __restrict__ h_in) {
  int col = blockIdx.x * 256 + threadIdx.x;
  int chunk = blockIdx.y;
  long r0 = (long)chunk * 64;
  float run = prefix[chunk * 1024 + col];
  for (int i = 0; i < 64; i++) {
    long row = r0 + i;
    float v = x[row * 1024 + col];
    unsigned char* hr = h_in + row * 3072;
    hr[col] = (unsigned char)f2e4m3(v);
    hr[1024 + col] = (unsigned char)(row == 0 ? 0u : f2e4m3(run));
    run = fmaxf(run, v);
  }
  float run2 = suffix[chunk * 1024 + col];
  for (int i = 63; i >= 0; i--) {
    long row = r0 + i;
    float v = x[row * 1024 + col];
    h_in[row * 3072 + 2048 + col] = (unsigned char)(row == 8191 ? 0u : f2e4m3(run2));
    run2 = fmaxf(run2, v);
  }
}

// ============ 256x256 FP8 GEMM (r8 schedule): h_act = relu(A@B^T * 1/32 + bias) bf16 ============
// r11 swizzle fix: r10's linear fp8 layout was an 8-way b64 conflict (1.32e8
// measured): lane bank = 16*(fr&1) + 2*(kk*4+fk); fixed fk piles 8 same-parity
// lanes on one 2-bank slot. Fix: byte ^= (row&6)<<3 (even XOR keeps 16-B staging
// chunks contiguous; bit0 of fr already splits bank halves via 64-B row stride).
// Uniformity: full wave 4 touches/bank = floor; per fixed-fk phase 2/bank = free.
// Both-sides: staging scol = (t&3)*16 ^ ((t>>2)&6)<<3; read xr = (fr&6)<<3.
__global__ __launch_bounds__(512, 2) void gemm256_relu(
    const unsigned char* __restrict__ A, const unsigned char* __restrict__ B,
    unsigned short* __restrict__ C, const float* __restrict__ bias,
    int M, int N, int K) {
  extern __shared__ char smem[];
  const int NT = K >> 6;

  const int nwg = gridDim.x;
  const int cpx = nwg >> 3;
  const int bid = blockIdx.x;
  const int swz = (bid & 7) * cpx + (bid >> 3);
  const int tiles_m = M >> 8;
  const int tm = swz % tiles_m;
  const int tn = swz / tiles_m;
  const long brow = (long)tm * 256;
  const long bcol = (long)tn * 256;

  const int t = threadIdx.x;
  const int lane = t & 63, wv = t >> 6;
  const int wr = wv >> 2, wc = wv & 3;
  const int fr = lane & 15, fk = lane >> 4;

  const int srow = t >> 2;
  const int scol = ((t & 3) * 16) ^ ((((t >> 2) & 6)) << 3);  // inverse swizzle
  const unsigned char* Asrc = A + (brow + srow) * (long)K + scol;
  const unsigned char* Bsrc = B + (bcol + srow) * (long)K + scol;
  const long hstep = (long)128 * K;

#define STAGE_A(j, reg, h)                                                     \
  __builtin_amdgcn_global_load_lds(AS1(Asrc + (h)*hstep + (j)*64),             \
      AS3(smem + (reg)*16384 + (h)*8192 + t * 16), 16, 0, 0)
#define STAGE_B(j, h)                                                          \
  __builtin_amdgcn_global_load_lds(AS1(Bsrc + (h)*hstep + (j)*64),             \
      AS3(smem + 49152 + ((j)&1) * 16384 + (h)*8192 + t * 16), 16, 0, 0)

  const int xr = (fr & 6) << 3;  // row&6 = fr&6 (other row terms have low3=0)
  const char* ArdRow = smem + (wr * 128 + fr) * 64;
  const char* BrdRow = smem + 49152 + (wc * 64 + fr) * 64;
#define RD_A(ar_, m, kk) \
  (*(const long*)(ArdRow + (ar_)*16384 + (m)*1024 + (((kk)*32 + fk * 8) ^ xr)))
#define RD_B(pb_, n, kk) \
  (*(const long*)(BrdRow + (pb_)*16384 + (n)*1024 + (((kk)*32 + fk * 8) ^ xr)))

#define MFMA_PAIR(mi, a_)                                                      \
  _Pragma("unroll")                                                            \
  for (int n = 0; n < 4; ++n) {                                                \
    acc[(mi)][n] = __builtin_amdgcn_mfma_f32_16x16x32_fp8_fp8(                 \
        a_[0], bfr[n][0], acc[(mi)][n], 0, 0, 0);                              \
    acc[(mi)][n] = __builtin_amdgcn_mfma_f32_16x16x32_fp8_fp8(                 \
        a_[1], bfr[n][1], acc[(mi)][n], 0, 0, 0);                              \
  }

  f32x4 acc[8][4];
#pragma unroll
  for (int m = 0; m < 8; m++)
#pragma unroll
    for (int n = 0; n < 4; n++) acc[m][n] = (f32x4)0.f;

  STAGE_A(0, 0, 0); STAGE_A(0, 0, 1); STAGE_B(0, 0); STAGE_B(0, 1);
  STAGE_A(1, 1, 0); STAGE_A(1, 1, 1); STAGE_B(1, 0); STAGE_B(1, 1);
  asm volatile("s_waitcnt vmcnt(4)" ::: "memory");
  __builtin_amdgcn_s_barrier();

  long bfr[4][2];
  long ap[2][2][2];
  ap[0][0][0] = RD_A(0, 0, 0); ap[0][0][1] = RD_A(0, 0, 1);
  ap[0][1][0] = RD_A(0, 1, 0); ap[0][1][1] = RD_A(0, 1, 1);

  int ar = 0;
  for (int g = 0; g < NT; ++g) {
    const int pb = g & 1;
    int sr = ar + 2; if (sr >= 3) sr -= 3;
    int nar = ar + 1; if (nar >= 3) nar = 0;
    const bool st = (g + 2 < NT);
#pragma unroll
    for (int p = 0; p < 4; ++p) {
      const int cs = p & 1, ns = cs ^ 1;
      if (p == 0) {
#pragma unroll
        for (int n = 0; n < 4; ++n) {
          bfr[n][0] = RD_B(pb, n, 0);
          bfr[n][1] = RD_B(pb, n, 1);
        }
      }
      asm volatile("s_waitcnt lgkmcnt(0)" ::: "memory");
      __builtin_amdgcn_sched_barrier(0);
      __builtin_amdgcn_s_setprio(1);
      MFMA_PAIR(2 * p, ap[cs][0])
      MFMA_PAIR(2 * p + 1, ap[cs][1])
      __builtin_amdgcn_s_setprio(0);
      if (p < 3) {
        ap[ns][0][0] = RD_A(ar, 2 * p + 2, 0); ap[ns][0][1] = RD_A(ar, 2 * p + 2, 1);
        ap[ns][1][0] = RD_A(ar, 2 * p + 3, 0); ap[ns][1][1] = RD_A(ar, 2 * p + 3, 1);
      } else if (g + 1 < NT) {
        ap[ns][0][0] = RD_A(nar, 0, 0); ap[ns][0][1] = RD_A(nar, 0, 1);
        ap[ns][1][0] = RD_A(nar, 1, 0); ap[ns][1][1] = RD_A(nar, 1, 1);
      }
      if (st) {
        if (p == 0) STAGE_A(g + 2, sr, 0);
        if (p == 1) STAGE_A(g + 2, sr, 1);
        if (p == 2) STAGE_B(g + 2, 0);
        if (p == 3) STAGE_B(g + 2, 1);
      }
      if (p == 2 && g + 1 < NT) {
        if (st) asm volatile("s_waitcnt vmcnt(3)" ::: "memory");
        else    asm volatile("s_waitcnt vmcnt(0)" ::: "memory");
      }
      asm volatile("s_barrier" ::: "memory");
    }
    ar = nar;
  }

  float bi[4];
#pragma unroll
  for (int n = 0; n < 4; ++n) bi[n] = bias[bcol + wc * 64 + n * 16 + fr];
  const long orow = brow + wr * 128 + fk * 4;
  const long ocol = bcol + wc * 64 + fr;
#pragma unroll
  for (int m = 0; m < 8; ++m)
#pragma unroll
    for (int n = 0; n < 4; ++n)
#pragma unroll
      for (int r = 0; r < 4; ++r) {
        float v = acc[m][n][r] * 0.03125f + bi[n];
        v = v > 0.f ? v : 0.f;
        C[(orow + m * 16 + r) * (long)N + ocol + n * 16] = f2bf(v);
      }
#undef STAGE_A
#undef STAGE_B
#undef RD_A
#undef RD_B
#undef MFMA_PAIR
}

// ============ 256x128 FP8 GEMM2: out = (A@B^T * 1/32 + bias)*gamma + resid ============
// Same r11 swizzle. LDS: A 3x16K, B 2x8K = 64KB -> 2 blocks/CU. Grid 8x32=256.
__global__ __launch_bounds__(512, 2) void gemm256_g2(
    const unsigned char* __restrict__ A, const unsigned char* __restrict__ B,
    float* __restrict__ Cf, const float* __restrict__ bias,
    const float* __restrict__ gamma, const float* __restrict__ resid,
    int M, int N, int K) {
  extern __shared__ char smem[];
  const int NT = K >> 6;

  const int nwg = gridDim.x;
  const int cpx = nwg >> 3;
  const int bid = blockIdx.x;
  const int swz = (bid & 7) * cpx + (bid >> 3);
  const int tiles_m = M >> 8;
  const int tm = swz % tiles_m;
  const int tn = swz / tiles_m;
  const long brow = (long)tm * 256;
  const long bcol = (long)tn * 128;

  const int t = threadIdx.x;
  const int lane = t & 63, wv = t >> 6;
  const int wr = wv >> 1, wc = wv & 1;
  const int fr = lane & 15, fk = lane >> 4;

  const int srow = t >> 2;
  const int scol = ((t & 3) * 16) ^ ((((t >> 2) & 6)) << 3);
  const unsigned char* Asrc = A + (brow + srow) * (long)K + scol;
  const unsigned char* Bsrc = B + (bcol + srow) * (long)K + scol;
  const long hstep = (long)128 * K;

#define STAGE_A2(j, reg, h)                                                    \
  __builtin_amdgcn_global_load_lds(AS1(Asrc + (h)*hstep + (j)*64),             \
      AS3(smem + (reg)*16384 + (h)*8192 + t * 16), 16, 0, 0)
#define STAGE_B2(j)                                                            \
  __builtin_amdgcn_global_load_lds(AS1(Bsrc + (j)*64),                         \
      AS3(smem + 49152 + ((j)&1) * 8192 + t * 16), 16, 0, 0)

  const int xr = (fr & 6) << 3;
  const char* ArdRow = smem + (wr * 64 + fr) * 64;
  const char* BrdRow = smem + 49152 + (wc * 64 + fr) * 64;
#define RD_A2(ar_, m, kk) \
  (*(const long*)(ArdRow + (ar_)*16384 + (m)*1024 + (((kk)*32 + fk * 8) ^ xr)))
#define RD_B2(pb_, n, kk) \
  (*(const long*)(BrdRow + (pb_)*8192 + (n)*1024 + (((kk)*32 + fk * 8) ^ xr)))

  f32x4 acc[4][4];
#pragma unroll
  for (int m = 0; m < 4; m++)
#pragma unroll
    for (int n = 0; n < 4; n++) acc[m][n] = (f32x4)0.f;

  STAGE_A2(0, 0, 0); STAGE_A2(0, 0, 1); STAGE_B2(0);
  STAGE_A2(1, 1, 0); STAGE_A2(1, 1, 1); STAGE_B2(1);
  asm volatile("s_waitcnt vmcnt(3)" ::: "memory");
  __builtin_amdgcn_s_barrier();

  long bfr[4][2];
  long ap[2][2];
  ap[0][0] = RD_A2(0, 0, 0); ap[0][1] = RD_A2(0, 0, 1);

  int ar = 0;
  for (int g = 0; g < NT; ++g) {
    const int pb = g & 1;
    int sr = ar + 2; if (sr >= 3) sr -= 3;
    int nar = ar + 1; if (nar >= 3) nar = 0;
    const bool st = (g + 2 < NT);
#pragma unroll
    for (int p = 0; p < 4; ++p) {
      const int cs = p & 1, ns = cs ^ 1;
      if (p == 0) {
#pragma unroll
        for (int n = 0; n < 4; ++n) {
          bfr[n][0] = RD_B2(pb, n, 0);
          bfr[n][1] = RD_B2(pb, n, 1);
        }
      }
      asm volatile("s_waitcnt lgkmcnt(0)" ::: "memory");
      __builtin_amdgcn_sched_barrier(0);
      __builtin_amdgcn_s_setprio(1);
#pragma unroll
      for (int n = 0; n < 4; ++n) {
        acc[p][n] = __builtin_amdgcn_mfma_f32_16x16x32_fp8_fp8(
            ap[cs][0], bfr[n][0], acc[p][n], 0, 0, 0);
        acc[p][n] = __builtin_amdgcn_mfma_f32_16x16x32_fp8_fp8(
            ap[cs][1], bfr[n][1], acc[p][n], 0, 0, 0);
      }
      __builtin_amdgcn_s_setprio(0);
      if (p < 3) {
        ap[ns][0] = RD_A2(ar, p + 1, 0); ap[ns][1] = RD_A2(ar, p + 1, 1);
      } else if (g + 1 < NT) {
        ap[ns][0] = RD_A2(nar, 0, 0); ap[ns][1] = RD_A2(nar, 0, 1);
      }
      if (st) {
        if (p == 0) STAGE_A2(g + 2, sr, 0);
        if (p == 1) STAGE_A2(g + 2, sr, 1);
        if (p == 2) STAGE_B2(g + 2);
      }
      if (p == 2 && g + 1 < NT) {
        if (st) asm volatile("s_waitcnt vmcnt(3)" ::: "memory");
        else    asm volatile("s_waitcnt vmcnt(0)" ::: "memory");
      }
      asm volatile("s_barrier" ::: "memory");
    }
    ar = nar;
  }

  float bi[4], ga[4];
#pragma unroll
  for (int n = 0; n < 4; ++n) {
    const long col = bcol + wc * 64 + n * 16 + fr;
    bi[n] = bias[col];
    ga[n] = gamma[col];
  }
  const long orow = brow + wr * 64 + fk * 4;
  const long ocol = bcol + wc * 64 + fr;
#pragma unroll
  for (int m = 0; m < 4; ++m)
#pragma unroll
    for (int n = 0; n < 4; ++n)
#pragma unroll
      for (int r = 0; r < 4; ++r) {
        const long row = orow + m * 16 + r;
        const long col = ocol + n * 16;
        Cf[row * (long)N + col] =
            (acc[m][n][r] * 0.03125f + bi[n]) * ga[n] + resid[row * (long)N + col];
      }
#undef STAGE_A2
#undef STAGE_B2
#undef RD_A2
#undef RD_B2
}

// ---------------- LayerNorm: reads bf16 h_act, writes FP8 h_ln ----------------
__global__ __launch_bounds__(256) void ln_fp8(const unsigned short* __restrict__ h,
                                              unsigned char* __restrict__ hq,
                                              const float* __restrict__ w,
                                              const float* __restrict__ b) {
  const unsigned short* hp = h + (long)blockIdx.x * 4096;
  const int tid = threadIdx.x;
  u16x8 a0 = ((const u16x8*)hp)[tid * 2];
  u16x8 a1 = ((const u16x8*)hp)[tid * 2 + 1];
  float v[16];
#pragma unroll
  for (int j = 0; j < 8; j++) { v[j] = bf2f(a0[j]); v[8 + j] = bf2f(a1[j]); }
  float s = 0.f, q = 0.f;
#pragma unroll
  for (int j = 0; j < 16; j++) { s += v[j]; q += v[j] * v[j]; }
#pragma unroll
  for (int off = 32; off; off >>= 1) {
    s += __shfl_xor(s, off, 64);
    q += __shfl_xor(q, off, 64);
  }
  __shared__ float ss[4], sq[4];
  const int wv = tid >> 6;
  if ((tid & 63) == 0) { ss[wv] = s; sq[wv] = q; }
  __syncthreads();
  s = ss[0] + ss[1] + ss[2] + ss[3];
  q = sq[0] + sq[1] + sq[2] + sq[3];
  const float mu = s * (1.f / 4096.f);
  const float var = q * (1.f / 4096.f) - mu * mu;
  const float rs = rsqrtf(var + 1e-6f);
  unsigned o[4] = {0, 0, 0, 0};
#pragma unroll
  for (int j = 0; j < 8; j++) {
    int c0 = tid * 16 + j, c1 = c0 + 8;
    float y0 = (v[j] - mu) * rs * w[c0] + b[c0];
    float y1 = (v[8 + j] - mu) * rs * w[c1] + b[c1];
    o[j >> 2] |= f2e4m3(y0) << ((j & 3) * 8);
    o[2 + (j >> 2)] |= f2e4m3(y1) << ((j & 3) * 8);
  }
  uint4 pk = {o[0], o[1], o[2], o[3]};
  *(uint4*)(hq + (long)blockIdx.x * 4096 + tid * 16) = pk;
}

extern "C" void kernel_launch(void* const* d_in, const int* in_sizes, int n_in,
                              void* d_out, int out_size, void* d_ws, size_t ws_size,
                              hipStream_t stream) {
  const float* x     = (const float*)d_in[0];
  const float* W1    = (const float*)d_in[1];
  const float* b1    = (const float*)d_in[2];
  const float* ln_w  = (const float*)d_in[3];
  const float* ln_b  = (const float*)d_in[4];
  const float* W2    = (const float*)d_in[5];
  const float* b2    = (const float*)d_in[6];
  const float* gamma = (const float*)d_in[7];
  float* out = (float*)d_out;

  const int Nr = 8192, DIM = 1024, DFF = 4096, K1 = 3072;

  unsigned char* W1q  = (unsigned char*)d_ws;
  unsigned char* W2q  = W1q + (long)DFF * K1;
  unsigned char* h_in = W2q + (long)DIM * DFF;
  unsigned short* h_act = (unsigned short*)(h_in + (long)Nr * K1);
  unsigned char* h_ln = (unsigned char*)(h_act + (long)Nr * DFF);
  float* partial = (float*)(h_ln + (long)Nr * DFF);
  float* prefix  = partial + 128 * 1024;
  float* suffix  = prefix + 128 * 1024;

  hipFuncSetAttribute((const void*)gemm256_relu,
                      hipFuncAttributeMaxDynamicSharedMemorySize, 81920);
  hipFuncSetAttribute((const void*)gemm256_g2,
                      hipFuncAttributeMaxDynamicSharedMemorySize, 65536);

  cast_fp8<<<2048, 256, 0, stream>>>(W1, W1q, (long)DFF * K1, 32.f);
  cast_fp8<<<1024, 256, 0, stream>>>(W2, W2q, (long)DIM * DFF, 32.f);

  scan_chunkmax<<<dim3(4, 128), 256, 0, stream>>>(x, partial);
  scan_chunkscan<<<4, 256, 0, stream>>>(partial, prefix, suffix);
  scan_emit<<<dim3(4, 128), 256, 0, stream>>>(x, prefix, suffix, h_in);

  // GEMM1: h_act = relu(h_in @ W1q^T / 32 + b1)  — fp8 + r11 swizzle
  gemm256_relu<<<512, 512, 81920, stream>>>(h_in, W1q, h_act, b1, Nr, DFF, K1);

  ln_fp8<<<Nr, 256, 0, stream>>>(h_act, h_ln, ln_w, ln_b);

  // GEMM2: out = (h_ln @ W2q^T / 32 + b2) * gamma + x  — fp8 + r11 swizzle
  gemm256_g2<<<256, 512, 65536, stream>>>(h_ln, W2q, out, b2, gamma, x,
                                          Nr, DIM, DFF);
}

// Round 12
// 351.011 us; speedup vs baseline: 1.7249x; 1.2646x over previous
//
#include <hip/hip_runtime.h>

typedef __attribute__((ext_vector_type(4))) float f32x4;
typedef __attribute__((ext_vector_type(8))) short s16x8;
typedef __attribute__((ext_vector_type(8))) unsigned short u16x8;

#define AS1(p) ((const __attribute__((address_space(1))) void*)(p))
#define AS3(p) ((__attribute__((address_space(3))) void*)(p))

__device__ __forceinline__ unsigned short f2bf(float f) {
  unsigned u = __builtin_bit_cast(unsigned, f);
  u += 0x7fffu + ((u >> 16) & 1u);   // RNE; inputs are finite
  return (unsigned short)(u >> 16);
}
__device__ __forceinline__ float bf2f(unsigned short s) {
  unsigned u = ((unsigned)s) << 16;
  return __builtin_bit_cast(float, u);
}

// ---------------- fp32 -> bf16 cast, both weight tensors in one launch ----------------
__global__ __launch_bounds__(256) void cast2_bf16(const float* __restrict__ in1,
                                                  unsigned short* __restrict__ out1,
                                                  long n1,
                                                  const float* __restrict__ in2,
                                                  unsigned short* __restrict__ out2,
                                                  long n2) {
  const float* in;
  unsigned short* out;
  long n, b0, nb;
  if (blockIdx.x < 1536) { in = in1; out = out1; n = n1; b0 = blockIdx.x; nb = 1536; }
  else                   { in = in2; out = out2; n = n2; b0 = blockIdx.x - 1536; nb = 512; }
  long i = (b0 * 256 + threadIdx.x) * 4;
  long stride = nb * 256 * 4;
  for (; i < n; i += stride) {
    float4 f = *(const float4*)(in + i);
    ushort4 o = { f2bf(f.x), f2bf(f.y), f2bf(f.z), f2bf(f.w) };
    *(ushort4*)(out + i) = o;
  }
}

// ---------------- hierarchical column cummax scan ----------------
__global__ __launch_bounds__(256) void scan_chunkmax(const float* __restrict__ x,
                                                     float* __restrict__ partial) {
  int col = blockIdx.x * 256 + threadIdx.x;
  int chunk = blockIdx.y;
  const float* p = x + (long)chunk * 64 * 1024 + col;
  float m = -INFINITY;
#pragma unroll 4
  for (int i = 0; i < 64; i++) m = fmaxf(m, p[(long)i * 1024]);
  partial[chunk * 1024 + col] = m;
}

// r12: register-batched — r9's version did 2x128 serial dependent-latency L2
// round-trips (~30 us on a 4-block grid). Load all 128 partials with independent
// (vmcnt-batched) loads, then scan in-register; static indices via full unroll.
__global__ __launch_bounds__(256) void scan_chunkscan(const float* __restrict__ partial,
                                                      float* __restrict__ prefix,
                                                      float* __restrict__ suffix) {
  int col = blockIdx.x * 256 + threadIdx.x;
  float v[128];
#pragma unroll
  for (int c = 0; c < 128; c++) v[c] = partial[c * 1024 + col];
  float run = -INFINITY;
#pragma unroll
  for (int c = 0; c < 128; c++) {
    prefix[c * 1024 + col] = run;
    run = fmaxf(run, v[c]);
  }
  run = -INFINITY;
#pragma unroll
  for (int c = 127; c >= 0; c--) {
    suffix[c * 1024 + col] = run;
    run = fmaxf(run, v[c]);
  }
}

__global__ __launch_bounds__(256) void scan_emit(const float* __restrict__ x,
                                                 const float* __restrict__ prefix,
                                                 const float* __restrict__ suffix,
                                                 unsigned short* __restrict__ h_in) {
  int col = blockIdx.x * 256 + threadIdx.x;
  int chunk = blockIdx.y;
  long r0 = (long)chunk * 64;
  float run = prefix[chunk * 1024 + col];
  for (int i = 0; i < 64; i++) {
    long row = r0 + i;
    float v = x[row * 1024 + col];
    unsigned short* hr = h_in + row * 3072;
    hr[col] = f2bf(v);
    hr[1024 + col] = f2bf(row == 0 ? 0.f : run);
    run = fmaxf(run, v);
  }
  float run2 = suffix[chunk * 1024 + col];
  for (int i = 63; i >= 0; i--) {
    long row = r0 + i;
    float v = x[row * 1024 + col];
    h_in[row * 3072 + 2048 + col] = f2bf(row == 8191 ? 0.f : run2);
    run2 = fmaxf(run2, v);
  }
}

// ============ 256x256 bf16 GEMM (r8 structure, best measured 189us/47%): relu(A@B^T+bias) ============
// B-read-ahead variant REJECTED by register math: acc 128 AGPR + 112 VGPR = 240
// of the 256/wave budget at 2 waves/SIMD; +64 VGPR for a second bfr set spills.
__global__ __launch_bounds__(512, 2) void gemm256_relu(
    const unsigned short* __restrict__ A, const unsigned short* __restrict__ B,
    unsigned short* __restrict__ C, const float* __restrict__ bias,
    int M, int N, int K) {
  extern __shared__ char smem[];
  const int NT = K >> 6;

  const int nwg = gridDim.x;
  const int cpx = nwg >> 3;
  const int bid = blockIdx.x;
  const int swz = (bid & 7) * cpx + (bid >> 3);
  const int tiles_m = M >> 8;
  const int tm = swz % tiles_m;
  const int tn = swz / tiles_m;
  const long brow = (long)tm * 256;
  const long bcol = (long)tn * 256;

  const int t = threadIdx.x;
  const int lane = t & 63, wv = t >> 6;
  const int wr = wv >> 2, wc = wv & 3;
  const int fr = lane & 15, fk = lane >> 4;

  const int srow = t >> 3;
  const int scol = 8 * ((t & 7) ^ ((t >> 3) & 7));
  const unsigned short* Asrc = A + (brow + srow) * (long)K + scol;
  const unsigned short* Bsrc = B + (bcol + srow) * (long)K + scol;
  const long hstep = (long)128 * K, lstep = (long)64 * K;

#define STAGE_A(j, reg, h, L)                                                  \
  __builtin_amdgcn_global_load_lds(AS1(Asrc + (h)*hstep + (L)*lstep + (j)*64), \
      AS3(smem + (reg)*32768 + (h)*16384 + (L)*8192 + t * 16), 16, 0, 0)
#define STAGE_B(j, h, L)                                                       \
  __builtin_amdgcn_global_load_lds(AS1(Bsrc + (h)*hstep + (L)*lstep + (j)*64), \
      AS3(smem + 98304 + ((j)&1) * 32768 + (h)*16384 + (L)*8192 + t * 16), 16, 0, 0)

  const int xr = (fr & 7) << 4;
  const char* ArdRow = smem + (wr * 128 + fr) * 128;
  const char* BrdRow = smem + 98304 + (wc * 64 + fr) * 128;
#define RD_A(ar_, m, kk) \
  (*(const s16x8*)(ArdRow + (ar_)*32768 + (m)*2048 + (((kk)*64 + fk * 16) ^ xr)))
#define RD_B(pb_, n, kk) \
  (*(const s16x8*)(BrdRow + (pb_)*32768 + (n)*2048 + (((kk)*64 + fk * 16) ^ xr)))

#define MFMA_PAIR(mi, a_)                                                      \
  _Pragma("unroll")                                                            \
  for (int n = 0; n < 4; ++n) {                                                \
    acc[(mi)][n] = __builtin_amdgcn_mfma_f32_16x16x32_bf16(                    \
        a_[0], bfr[n][0], acc[(mi)][n], 0, 0, 0);                              \
    acc[(mi)][n] = __builtin_amdgcn_mfma_f32_16x16x32_bf16(                    \
        a_[1], bfr[n][1], acc[(mi)][n], 0, 0, 0);                              \
  }

  f32x4 acc[8][4];
#pragma unroll
  for (int m = 0; m < 8; m++)
#pragma unroll
    for (int n = 0; n < 4; n++) acc[m][n] = (f32x4)0.f;

  STAGE_A(0, 0, 0, 0); STAGE_A(0, 0, 0, 1); STAGE_A(0, 0, 1, 0); STAGE_A(0, 0, 1, 1);
  STAGE_B(0, 0, 0); STAGE_B(0, 0, 1); STAGE_B(0, 1, 0); STAGE_B(0, 1, 1);
  STAGE_A(1, 1, 0, 0); STAGE_A(1, 1, 0, 1); STAGE_A(1, 1, 1, 0); STAGE_A(1, 1, 1, 1);
  STAGE_B(1, 0, 0); STAGE_B(1, 0, 1); STAGE_B(1, 1, 0); STAGE_B(1, 1, 1);
  asm volatile("s_waitcnt vmcnt(8)" ::: "memory");
  __builtin_amdgcn_s_barrier();

  s16x8 bfr[4][2];
  s16x8 ap[2][2][2];
  ap[0][0][0] = RD_A(0, 0, 0); ap[0][0][1] = RD_A(0, 0, 1);
  ap[0][1][0] = RD_A(0, 1, 0); ap[0][1][1] = RD_A(0, 1, 1);

  int ar = 0;
  for (int g = 0; g < NT; ++g) {
    const int pb = g & 1;
    int sr = ar + 2; if (sr >= 3) sr -= 3;
    int nar = ar + 1; if (nar >= 3) nar = 0;
    const bool st = (g + 2 < NT);
#pragma unroll
    for (int p = 0; p < 4; ++p) {
      const int cs = p & 1, ns = cs ^ 1;
      if (p == 0) {
#pragma unroll
        for (int n = 0; n < 4; ++n) {
          bfr[n][0] = RD_B(pb, n, 0);
          bfr[n][1] = RD_B(pb, n, 1);
        }
      }
      asm volatile("s_waitcnt lgkmcnt(0)" ::: "memory");
      __builtin_amdgcn_sched_barrier(0);
      __builtin_amdgcn_s_setprio(1);
      MFMA_PAIR(2 * p, ap[cs][0])
      MFMA_PAIR(2 * p + 1, ap[cs][1])
      __builtin_amdgcn_s_setprio(0);
      if (p < 3) {
        ap[ns][0][0] = RD_A(ar, 2 * p + 2, 0); ap[ns][0][1] = RD_A(ar, 2 * p + 2, 1);
        ap[ns][1][0] = RD_A(ar, 2 * p + 3, 0); ap[ns][1][1] = RD_A(ar, 2 * p + 3, 1);
      } else if (g + 1 < NT) {
        ap[ns][0][0] = RD_A(nar, 0, 0); ap[ns][0][1] = RD_A(nar, 0, 1);
        ap[ns][1][0] = RD_A(nar, 1, 0); ap[ns][1][1] = RD_A(nar, 1, 1);
      }
      if (st) {
        if (p == 0) { STAGE_A(g + 2, sr, 0, 0); STAGE_A(g + 2, sr, 0, 1); }
        if (p == 1) { STAGE_A(g + 2, sr, 1, 0); STAGE_A(g + 2, sr, 1, 1); }
        if (p == 2) { STAGE_B(g + 2, 0, 0); STAGE_B(g + 2, 0, 1); }
        if (p == 3) { STAGE_B(g + 2, 1, 0); STAGE_B(g + 2, 1, 1); }
      }
      if (p == 2 && g + 1 < NT) {
        if (st) asm volatile("s_waitcnt vmcnt(6)" ::: "memory");
        else    asm volatile("s_waitcnt vmcnt(0)" ::: "memory");
      }
      asm volatile("s_barrier" ::: "memory");
    }
    ar = nar;
  }

  float bi[4];
#pragma unroll
  for (int n = 0; n < 4; ++n) bi[n] = bias[bcol + wc * 64 + n * 16 + fr];
  const long orow = brow + wr * 128 + fk * 4;
  const long ocol = bcol + wc * 64 + fr;
#pragma unroll
  for (int m = 0; m < 8; ++m)
#pragma unroll
    for (int n = 0; n < 4; ++n)
#pragma unroll
      for (int r = 0; r < 4; ++r) {
        float v = acc[m][n][r] + bi[n];
        v = v > 0.f ? v : 0.f;
        C[(orow + m * 16 + r) * (long)N + ocol + n * 16] = f2bf(v);
      }
#undef STAGE_A
#undef STAGE_B
#undef RD_A
#undef RD_B
#undef MFMA_PAIR
}

// ============ 256x128-tile GEMM2 (r9, best measured): Cf = (A@B^T + bias)*gamma + resid ============
__global__ __launch_bounds__(512, 2) void gemm256_g2(
    const unsigned short* __restrict__ A, const unsigned short* __restrict__ B,
    float* __restrict__ Cf, const float* __restrict__ bias,
    const float* __restrict__ gamma, const float* __restrict__ resid,
    int M, int N, int K) {
  extern __shared__ char smem[];
  const int NT = K >> 6;

  const int nwg = gridDim.x;
  const int cpx = nwg >> 3;
  const int bid = blockIdx.x;
  const int swz = (bid & 7) * cpx + (bid >> 3);
  const int tiles_m = M >> 8;
  const int tm = swz % tiles_m;
  const int tn = swz / tiles_m;
  const long brow = (long)tm * 256;
  const long bcol = (long)tn * 128;

  const int t = threadIdx.x;
  const int lane = t & 63, wv = t >> 6;
  const int wr = wv >> 1, wc = wv & 1;
  const int fr = lane & 15, fk = lane >> 4;

  const int srow = t >> 3;
  const int scol = 8 * ((t & 7) ^ ((t >> 3) & 7));
  const unsigned short* Asrc = A + (brow + srow) * (long)K + scol;
  const unsigned short* Bsrc = B + (bcol + srow) * (long)K + scol;
  const long hstep = (long)128 * K, lstep = (long)64 * K;

#define STAGE_A2(j, reg, h, L)                                                 \
  __builtin_amdgcn_global_load_lds(AS1(Asrc + (h)*hstep + (L)*lstep + (j)*64), \
      AS3(smem + (reg)*32768 + (h)*16384 + (L)*8192 + t * 16), 16, 0, 0)
#define STAGE_B2(j, L)                                                         \
  __builtin_amdgcn_global_load_lds(AS1(Bsrc + (L)*lstep + (j)*64),             \
      AS3(smem + 98304 + ((j)&1) * 16384 + (L)*8192 + t * 16), 16, 0, 0)

  const int xr = (fr & 7) << 4;
  const char* ArdRow = smem + (wr * 64 + fr) * 128;
  const char* BrdRow = smem + 98304 + (wc * 64 + fr) * 128;
#define RD_A2(ar_, m, kk) \
  (*(const s16x8*)(ArdRow + (ar_)*32768 + (m)*2048 + (((kk)*64 + fk * 16) ^ xr)))
#define RD_B2(pb_, n, kk) \
  (*(const s16x8*)(BrdRow + (pb_)*16384 + (n)*2048 + (((kk)*64 + fk * 16) ^ xr)))

  f32x4 acc[4][4];
#pragma unroll
  for (int m = 0; m < 4; m++)
#pragma unroll
    for (int n = 0; n < 4; n++) acc[m][n] = (f32x4)0.f;

  STAGE_A2(0, 0, 0, 0); STAGE_A2(0, 0, 0, 1); STAGE_A2(0, 0, 1, 0); STAGE_A2(0, 0, 1, 1);
  STAGE_B2(0, 0); STAGE_B2(0, 1);
  STAGE_A2(1, 1, 0, 0); STAGE_A2(1, 1, 0, 1); STAGE_A2(1, 1, 1, 0); STAGE_A2(1, 1, 1, 1);
  STAGE_B2(1, 0); STAGE_B2(1, 1);
  asm volatile("s_waitcnt vmcnt(6)" ::: "memory");
  __builtin_amdgcn_s_barrier();

  s16x8 bfr[4][2];
  s16x8 ap[2][2];
  ap[0][0] = RD_A2(0, 0, 0); ap[0][1] = RD_A2(0, 0, 1);

  int ar = 0;
  for (int g = 0; g < NT; ++g) {
    const int pb = g & 1;
    int sr = ar + 2; if (sr >= 3) sr -= 3;
    int nar = ar + 1; if (nar >= 3) nar = 0;
    const bool st = (g + 2 < NT);
#pragma unroll
    for (int p = 0; p < 4; ++p) {
      const int cs = p & 1, ns = cs ^ 1;
      if (p == 0) {
#pragma unroll
        for (int n = 0; n < 4; ++n) {
          bfr[n][0] = RD_B2(pb, n, 0);
          bfr[n][1] = RD_B2(pb, n, 1);
        }
      }
      asm volatile("s_waitcnt lgkmcnt(0)" ::: "memory");
      __builtin_amdgcn_sched_barrier(0);
      __builtin_amdgcn_s_setprio(1);
#pragma unroll
      for (int n = 0; n < 4; ++n) {
        acc[p][n] = __builtin_amdgcn_mfma_f32_16x16x32_bf16(
            ap[cs][0], bfr[n][0], acc[p][n], 0, 0, 0);
        acc[p][n] = __builtin_amdgcn_mfma_f32_16x16x32_bf16(
            ap[cs][1], bfr[n][1], acc[p][n], 0, 0, 0);
      }
      __builtin_amdgcn_s_setprio(0);
      if (p < 3) {
        ap[ns][0] = RD_A2(ar, p + 1, 0); ap[ns][1] = RD_A2(ar, p + 1, 1);
      } else if (g + 1 < NT) {
        ap[ns][0] = RD_A2(nar, 0, 0); ap[ns][1] = RD_A2(nar, 0, 1);
      }
      if (st) {
        if (p == 0) { STAGE_A2(g + 2, sr, 0, 0); STAGE_A2(g + 2, sr, 0, 1); }
        if (p == 1) { STAGE_A2(g + 2, sr, 1, 0); STAGE_A2(g + 2, sr, 1, 1); }
        if (p == 2) { STAGE_B2(g + 2, 0); STAGE_B2(g + 2, 1); }
      }
      if (p == 2 && g + 1 < NT) {
        if (st) asm volatile("s_waitcnt vmcnt(6)" ::: "memory");
        else    asm volatile("s_waitcnt vmcnt(0)" ::: "memory");
      }
      asm volatile("s_barrier" ::: "memory");
    }
    ar = nar;
  }

  float bi[4], ga[4];
#pragma unroll
  for (int n = 0; n < 4; ++n) {
    const long col = bcol + wc * 64 + n * 16 + fr;
    bi[n] = bias[col];
    ga[n] = gamma[col];
  }
  const long orow = brow + wr * 64 + fk * 4;
  const long ocol = bcol + wc * 64 + fr;
#pragma unroll
  for (int m = 0; m < 4; ++m)
#pragma unroll
    for (int n = 0; n < 4; ++n)
#pragma unroll
      for (int r = 0; r < 4; ++r) {
        const long row = orow + m * 16 + r;
        const long col = ocol + n * 16;
        Cf[row * (long)N + col] = (acc[m][n][r] + bi[n]) * ga[n] + resid[row * (long)N + col];
      }
#undef STAGE_A2
#undef STAGE_B2
#undef RD_A2
#undef RD_B2
}

// ---------------- in-place LayerNorm over D=4096, one block per row ----------------
__global__ __launch_bounds__(256) void ln_inplace(unsigned short* __restrict__ h,
                                                  const float* __restrict__ w,
                                                  const float* __restrict__ b) {
  unsigned short* hp = h + (long)blockIdx.x * 4096;
  const int tid = threadIdx.x;
  u16x8 a0 = ((const u16x8*)hp)[tid * 2];
  u16x8 a1 = ((const u16x8*)hp)[tid * 2 + 1];
  float v[16];
#pragma unroll
  for (int j = 0; j < 8; j++) { v[j] = bf2f(a0[j]); v[8 + j] = bf2f(a1[j]); }
  float s = 0.f, q = 0.f;
#pragma unroll
  for (int j = 0; j < 16; j++) { s += v[j]; q += v[j] * v[j]; }
#pragma unroll
  for (int off = 32; off; off >>= 1) {
    s += __shfl_xor(s, off, 64);
    q += __shfl_xor(q, off, 64);
  }
  __shared__ float ss[4], sq[4];
  const int wv = tid >> 6;
  if ((tid & 63) == 0) { ss[wv] = s; sq[wv] = q; }
  __syncthreads();
  s = ss[0] + ss[1] + ss[2] + ss[3];
  q = sq[0] + sq[1] + sq[2] + sq[3];
  const float mu = s * (1.f / 4096.f);
  const float var = q * (1.f / 4096.f) - mu * mu;
  const float rs = rsqrtf(var + 1e-6f);
  u16x8 o0, o1;
#pragma unroll
  for (int j = 0; j < 8; j++) {
    int c0 = tid * 16 + j, c1 = c0 + 8;
    o0[j] = f2bf((v[j] - mu) * rs * w[c0] + b[c0]);
    o1[j] = f2bf((v[8 + j] - mu) * rs * w[c1] + b[c1]);
  }
  ((u16x8*)hp)[tid * 2] = o0;
  ((u16x8*)hp)[tid * 2 + 1] = o1;
}

extern "C" void kernel_launch(void* const* d_in, const int* in_sizes, int n_in,
                              void* d_out, int out_size, void* d_ws, size_t ws_size,
                              hipStream_t stream) {
  const float* x     = (const float*)d_in[0];
  const float* W1    = (const float*)d_in[1];
  const float* b1    = (const float*)d_in[2];
  const float* ln_w  = (const float*)d_in[3];
  const float* ln_b  = (const float*)d_in[4];
  const float* W2    = (const float*)d_in[5];
  const float* b2    = (const float*)d_in[6];
  const float* gamma = (const float*)d_in[7];
  float* out = (float*)d_out;

  const int Nr = 8192, DIM = 1024, DFF = 4096, K1 = 3072;

  unsigned short* W1b  = (unsigned short*)d_ws;
  unsigned short* W2b  = W1b + (long)DFF * K1;
  unsigned short* h_in = W2b + (long)DIM * DFF;
  unsigned short* h_act = h_in + (long)Nr * K1;
  float* partial = (float*)(h_act + (long)Nr * DFF);
  float* prefix  = partial + 128 * 1024;
  float* suffix  = prefix + 128 * 1024;

  hipFuncSetAttribute((const void*)gemm256_relu,
                      hipFuncAttributeMaxDynamicSharedMemorySize, 163840);
  hipFuncSetAttribute((const void*)gemm256_g2,
                      hipFuncAttributeMaxDynamicSharedMemorySize, 131072);

  cast2_bf16<<<2048, 256, 0, stream>>>(W1, W1b, (long)DFF * K1,
                                       W2, W2b, (long)DIM * DFF);

  scan_chunkmax<<<dim3(4, 128), 256, 0, stream>>>(x, partial);
  scan_chunkscan<<<4, 256, 0, stream>>>(partial, prefix, suffix);
  scan_emit<<<dim3(4, 128), 256, 0, stream>>>(x, prefix, suffix, h_in);

  // GEMM1: h_act = relu(h_in @ W1^T + b1)  — 256^2 r8 structure, grid 512
  gemm256_relu<<<512, 512, 163840, stream>>>(h_in, W1b, h_act, b1, Nr, DFF, K1);

  ln_inplace<<<Nr, 256, 0, stream>>>(h_act, ln_w, ln_b);

  // GEMM2: out = (h_act @ W2^T + b2) * gamma + x  — 256x128 r9 structure, grid 256
  gemm256_g2<<<256, 512, 131072, stream>>>(h_act, W2b, out, b2, gamma, x,
                                           Nr, DIM, DFF);
}

// Round 13
// 337.602 us; speedup vs baseline: 1.7934x; 1.0397x over previous
//
#include <hip/hip_runtime.h>

typedef __attribute__((ext_vector_type(4))) float f32x4;
typedef __attribute__((ext_vector_type(8))) short s16x8;
typedef __attribute__((ext_vector_type(8))) unsigned short u16x8;

#define AS1(p) ((const __attribute__((address_space(1))) void*)(p))
#define AS3(p) ((__attribute__((address_space(3))) void*)(p))

__device__ __forceinline__ unsigned short f2bf(float f) {
  unsigned u = __builtin_bit_cast(unsigned, f);
  u += 0x7fffu + ((u >> 16) & 1u);   // RNE; inputs are finite
  return (unsigned short)(u >> 16);
}
__device__ __forceinline__ float bf2f(unsigned short s) {
  unsigned u = ((unsigned)s) << 16;
  return __builtin_bit_cast(float, u);
}

// ---------------- fp32 -> bf16 cast, both weight tensors in one launch ----------------
__global__ __launch_bounds__(256) void cast2_bf16(const float* __restrict__ in1,
                                                  unsigned short* __restrict__ out1,
                                                  long n1,
                                                  const float* __restrict__ in2,
                                                  unsigned short* __restrict__ out2,
                                                  long n2) {
  const float* in;
  unsigned short* out;
  long n, b0, nb;
  if (blockIdx.x < 1536) { in = in1; out = out1; n = n1; b0 = blockIdx.x; nb = 1536; }
  else                   { in = in2; out = out2; n = n2; b0 = blockIdx.x - 1536; nb = 512; }
  long i = (b0 * 256 + threadIdx.x) * 4;
  long stride = nb * 256 * 4;
  for (; i < n; i += stride) {
    float4 f = *(const float4*)(in + i);
    ushort4 o = { f2bf(f.x), f2bf(f.y), f2bf(f.z), f2bf(f.w) };
    *(ushort4*)(out + i) = o;
  }
}

// ---------------- LN fold: w2l = W2 @ lnw, b2l = W2 @ lnb (per out-col) ----------------
__global__ __launch_bounds__(256) void w2_fold(const float* __restrict__ W2,
                                               const float* __restrict__ lnw,
                                               const float* __restrict__ lnb,
                                               float* __restrict__ w2l,
                                               float* __restrict__ b2l) {
  const int n = blockIdx.x;
  const float* w = W2 + (long)n * 4096;
  float s = 0.f, b = 0.f;
  for (int k = threadIdx.x; k < 4096; k += 256) {
    float wv = w[k];
    s += wv * lnw[k];
    b += wv * lnb[k];
  }
#pragma unroll
  for (int off = 32; off; off >>= 1) {
    s += __shfl_xor(s, off, 64);
    b += __shfl_xor(b, off, 64);
  }
  __shared__ float ss[4], bb[4];
  const int wv2 = threadIdx.x >> 6;
  if ((threadIdx.x & 63) == 0) { ss[wv2] = s; bb[wv2] = b; }
  __syncthreads();
  if (threadIdx.x == 0) {
    w2l[n] = ss[0] + ss[1] + ss[2] + ss[3];
    b2l[n] = bb[0] + bb[1] + bb[2] + bb[3];
  }
}

// ---------------- hierarchical column cummax scan ----------------
__global__ __launch_bounds__(256) void scan_chunkmax(const float* __restrict__ x,
                                                     float* __restrict__ partial) {
  int col = blockIdx.x * 256 + threadIdx.x;
  int chunk = blockIdx.y;
  const float* p = x + (long)chunk * 64 * 1024 + col;
  float m = -INFINITY;
#pragma unroll 4
  for (int i = 0; i < 64; i++) m = fmaxf(m, p[(long)i * 1024]);
  partial[chunk * 1024 + col] = m;
}

__global__ __launch_bounds__(256) void scan_chunkscan(const float* __restrict__ partial,
                                                      float* __restrict__ prefix,
                                                      float* __restrict__ suffix) {
  int col = blockIdx.x * 256 + threadIdx.x;
  float v[128];
#pragma unroll
  for (int c = 0; c < 128; c++) v[c] = partial[c * 1024 + col];
  float run = -INFINITY;
#pragma unroll
  for (int c = 0; c < 128; c++) {
    prefix[c * 1024 + col] = run;
    run = fmaxf(run, v[c]);
  }
  run = -INFINITY;
#pragma unroll
  for (int c = 127; c >= 0; c--) {
    suffix[c * 1024 + col] = run;
    run = fmaxf(run, v[c]);
  }
}

__global__ __launch_bounds__(256) void scan_emit(const float* __restrict__ x,
                                                 const float* __restrict__ prefix,
                                                 const float* __restrict__ suffix,
                                                 unsigned short* __restrict__ h_in) {
  int col = blockIdx.x * 256 + threadIdx.x;
  int chunk = blockIdx.y;
  long r0 = (long)chunk * 64;
  float run = prefix[chunk * 1024 + col];
  for (int i = 0; i < 64; i++) {
    long row = r0 + i;
    float v = x[row * 1024 + col];
    unsigned short* hr = h_in + row * 3072;
    hr[col] = f2bf(v);
    hr[1024 + col] = f2bf(row == 0 ? 0.f : run);
    run = fmaxf(run, v);
  }
  float run2 = suffix[chunk * 1024 + col];
  for (int i = 63; i >= 0; i--) {
    long row = r0 + i;
    float v = x[row * 1024 + col];
    h_in[row * 3072 + 2048 + col] = f2bf(row == 8191 ? 0.f : run2);
    run2 = fmaxf(run2, v);
  }
}

// ---------------- rowstats reducer: (mu, rs) per row from 16 col-block partials ----------------
__global__ __launch_bounds__(256) void ln_stats_reduce(const float* __restrict__ pp,
                                                       float* __restrict__ rowstats) {
  int row = blockIdx.x * 256 + threadIdx.x;  // grid 32
  int tm = row >> 8, rl = row & 255;
  float s = 0.f, q = 0.f;
#pragma unroll
  for (int tn = 0; tn < 16; ++tn) {
    const float* p = pp + (((long)(tm * 16 + tn) * 256 + rl) * 2);
    s += p[0];
    q += p[1];
  }
  float mu = s * (1.f / 4096.f);
  float var = q * (1.f / 4096.f) - mu * mu;
  rowstats[row * 2] = mu;
  rowstats[row * 2 + 1] = rsqrtf(var + 1e-6f);
}

// ============ 256x256 bf16 GEMM (r8 structure): h' = relu(A@B^T+bias)*lnw, + LN stats ============
// r13: epilogue fusion — writes h'=v*lnw (LN weight pre-applied; LN commutes through
// GEMM2 as rs*G - rs*mu*(W2@lnw) + (W2@lnb)) and emits per-(row, colblock) partial
// sums of v, v^2 -> pp (deterministic, no float atomics). Main loop untouched.
__global__ __launch_bounds__(512, 2) void gemm256_relu(
    const unsigned short* __restrict__ A, const unsigned short* __restrict__ B,
    unsigned short* __restrict__ C, const float* __restrict__ bias,
    const float* __restrict__ lnw, float* __restrict__ pp,
    int M, int N, int K) {
  extern __shared__ char smem[];
  const int NT = K >> 6;

  const int nwg = gridDim.x;
  const int cpx = nwg >> 3;
  const int bid = blockIdx.x;
  const int swz = (bid & 7) * cpx + (bid >> 3);
  const int tiles_m = M >> 8;
  const int tm = swz % tiles_m;
  const int tn = swz / tiles_m;
  const long brow = (long)tm * 256;
  const long bcol = (long)tn * 256;

  const int t = threadIdx.x;
  const int lane = t & 63, wv = t >> 6;
  const int wr = wv >> 2, wc = wv & 3;
  const int fr = lane & 15, fk = lane >> 4;

  const int srow = t >> 3;
  const int scol = 8 * ((t & 7) ^ ((t >> 3) & 7));
  const unsigned short* Asrc = A + (brow + srow) * (long)K + scol;
  const unsigned short* Bsrc = B + (bcol + srow) * (long)K + scol;
  const long hstep = (long)128 * K, lstep = (long)64 * K;

#define STAGE_A(j, reg, h, L)                                                  \
  __builtin_amdgcn_global_load_lds(AS1(Asrc + (h)*hstep + (L)*lstep + (j)*64), \
      AS3(smem + (reg)*32768 + (h)*16384 + (L)*8192 + t * 16), 16, 0, 0)
#define STAGE_B(j, h, L)                                                       \
  __builtin_amdgcn_global_load_lds(AS1(Bsrc + (h)*hstep + (L)*lstep + (j)*64), \
      AS3(smem + 98304 + ((j)&1) * 32768 + (h)*16384 + (L)*8192 + t * 16), 16, 0, 0)

  const int xr = (fr & 7) << 4;
  const char* ArdRow = smem + (wr * 128 + fr) * 128;
  const char* BrdRow = smem + 98304 + (wc * 64 + fr) * 128;
#define RD_A(ar_, m, kk) \
  (*(const s16x8*)(ArdRow + (ar_)*32768 + (m)*2048 + (((kk)*64 + fk * 16) ^ xr)))
#define RD_B(pb_, n, kk) \
  (*(const s16x8*)(BrdRow + (pb_)*32768 + (n)*2048 + (((kk)*64 + fk * 16) ^ xr)))

#define MFMA_PAIR(mi, a_)                                                      \
  _Pragma("unroll")                                                            \
  for (int n = 0; n < 4; ++n) {                                                \
    acc[(mi)][n] = __builtin_amdgcn_mfma_f32_16x16x32_bf16(                    \
        a_[0], bfr[n][0], acc[(mi)][n], 0, 0, 0);                              \
    acc[(mi)][n] = __builtin_amdgcn_mfma_f32_16x16x32_bf16(                    \
        a_[1], bfr[n][1], acc[(mi)][n], 0, 0, 0);                              \
  }

  f32x4 acc[8][4];
#pragma unroll
  for (int m = 0; m < 8; m++)
#pragma unroll
    for (int n = 0; n < 4; n++) acc[m][n] = (f32x4)0.f;

  STAGE_A(0, 0, 0, 0); STAGE_A(0, 0, 0, 1); STAGE_A(0, 0, 1, 0); STAGE_A(0, 0, 1, 1);
  STAGE_B(0, 0, 0); STAGE_B(0, 0, 1); STAGE_B(0, 1, 0); STAGE_B(0, 1, 1);
  STAGE_A(1, 1, 0, 0); STAGE_A(1, 1, 0, 1); STAGE_A(1, 1, 1, 0); STAGE_A(1, 1, 1, 1);
  STAGE_B(1, 0, 0); STAGE_B(1, 0, 1); STAGE_B(1, 1, 0); STAGE_B(1, 1, 1);
  asm volatile("s_waitcnt vmcnt(8)" ::: "memory");
  __builtin_amdgcn_s_barrier();

  s16x8 bfr[4][2];
  s16x8 ap[2][2][2];
  ap[0][0][0] = RD_A(0, 0, 0); ap[0][0][1] = RD_A(0, 0, 1);
  ap[0][1][0] = RD_A(0, 1, 0); ap[0][1][1] = RD_A(0, 1, 1);

  int ar = 0;
  for (int g = 0; g < NT; ++g) {
    const int pb = g & 1;
    int sr = ar + 2; if (sr >= 3) sr -= 3;
    int nar = ar + 1; if (nar >= 3) nar = 0;
    const bool st = (g + 2 < NT);
#pragma unroll
    for (int p = 0; p < 4; ++p) {
      const int cs = p & 1, ns = cs ^ 1;
      if (p == 0) {
#pragma unroll
        for (int n = 0; n < 4; ++n) {
          bfr[n][0] = RD_B(pb, n, 0);
          bfr[n][1] = RD_B(pb, n, 1);
        }
      }
      asm volatile("s_waitcnt lgkmcnt(0)" ::: "memory");
      __builtin_amdgcn_sched_barrier(0);
      __builtin_amdgcn_s_setprio(1);
      MFMA_PAIR(2 * p, ap[cs][0])
      MFMA_PAIR(2 * p + 1, ap[cs][1])
      __builtin_amdgcn_s_setprio(0);
      if (p < 3) {
        ap[ns][0][0] = RD_A(ar, 2 * p + 2, 0); ap[ns][0][1] = RD_A(ar, 2 * p + 2, 1);
        ap[ns][1][0] = RD_A(ar, 2 * p + 3, 0); ap[ns][1][1] = RD_A(ar, 2 * p + 3, 1);
      } else if (g + 1 < NT) {
        ap[ns][0][0] = RD_A(nar, 0, 0); ap[ns][0][1] = RD_A(nar, 0, 1);
        ap[ns][1][0] = RD_A(nar, 1, 0); ap[ns][1][1] = RD_A(nar, 1, 1);
      }
      if (st) {
        if (p == 0) { STAGE_A(g + 2, sr, 0, 0); STAGE_A(g + 2, sr, 0, 1); }
        if (p == 1) { STAGE_A(g + 2, sr, 1, 0); STAGE_A(g + 2, sr, 1, 1); }
        if (p == 2) { STAGE_B(g + 2, 0, 0); STAGE_B(g + 2, 0, 1); }
        if (p == 3) { STAGE_B(g + 2, 1, 0); STAGE_B(g + 2, 1, 1); }
      }
      if (p == 2 && g + 1 < NT) {
        if (st) asm volatile("s_waitcnt vmcnt(6)" ::: "memory");
        else    asm volatile("s_waitcnt vmcnt(0)" ::: "memory");
      }
      asm volatile("s_barrier" ::: "memory");
    }
    ar = nar;
  }

  // ---- fused epilogue: h' = relu(acc+bias)*lnw; per-row partial sums of v, v^2 ----
  float bi[4], lw[4];
#pragma unroll
  for (int n = 0; n < 4; ++n) {
    const long col = bcol + wc * 64 + n * 16 + fr;
    bi[n] = bias[col];
    lw[n] = lnw[col];
  }
  float* sred = (float*)smem;          // [256][4]
  float* qred = sred + 1024;           // [256][4]
  const long orow = brow + wr * 128 + fk * 4;
  const long ocol = bcol + wc * 64 + fr;
#pragma unroll
  for (int m = 0; m < 8; ++m) {
#pragma unroll
    for (int r = 0; r < 4; ++r) {
      const long row = orow + m * 16 + r;
      float s = 0.f, q = 0.f;
#pragma unroll
      for (int n = 0; n < 4; ++n) {
        float v = acc[m][n][r] + bi[n];
        v = v > 0.f ? v : 0.f;
        s += v;
        q += v * v;
        C[row * (long)N + ocol + n * 16] = f2bf(v * lw[n]);
      }
#pragma unroll
      for (int off = 1; off < 16; off <<= 1) {
        s += __shfl_xor(s, off, 64);
        q += __shfl_xor(q, off, 64);
      }
      if (fr == 0) {
        int rl = wr * 128 + m * 16 + fk * 4 + r;
        sred[rl * 4 + wc] = s;
        qred[rl * 4 + wc] = q;
      }
    }
  }
  __syncthreads();
  if (t < 256) {
    float s = sred[t * 4] + sred[t * 4 + 1] + sred[t * 4 + 2] + sred[t * 4 + 3];
    float q = qred[t * 4] + qred[t * 4 + 1] + qred[t * 4 + 2] + qred[t * 4 + 3];
    float* pb = pp + (((long)(tm * 16 + tn) * 256 + t) * 2);
    pb[0] = s;
    pb[1] = q;
  }
#undef STAGE_A
#undef STAGE_B
#undef RD_A
#undef RD_B
#undef MFMA_PAIR
}

// ============ 256x128-tile GEMM2 (r9): out = (rs*G - rs*mu*w2l + b2l + b2)*gamma + x ============
// A = h' (lnw pre-applied). LN applied algebraically in the epilogue via rowstats.
__global__ __launch_bounds__(512, 2) void gemm256_g2(
    const unsigned short* __restrict__ A, const unsigned short* __restrict__ B,
    float* __restrict__ Cf, const float* __restrict__ bias,
    const float* __restrict__ gamma, const float* __restrict__ resid,
    const float* __restrict__ w2l, const float* __restrict__ b2l,
    const float* __restrict__ rowstats,
    int M, int N, int K) {
  extern __shared__ char smem[];
  const int NT = K >> 6;

  const int nwg = gridDim.x;
  const int cpx = nwg >> 3;
  const int bid = blockIdx.x;
  const int swz = (bid & 7) * cpx + (bid >> 3);
  const int tiles_m = M >> 8;
  const int tm = swz % tiles_m;
  const int tn = swz / tiles_m;
  const long brow = (long)tm * 256;
  const long bcol = (long)tn * 128;

  const int t = threadIdx.x;
  const int lane = t & 63, wv = t >> 6;
  const int wr = wv >> 1, wc = wv & 1;
  const int fr = lane & 15, fk = lane >> 4;

  const int srow = t >> 3;
  const int scol = 8 * ((t & 7) ^ ((t >> 3) & 7));
  const unsigned short* Asrc = A + (brow + srow) * (long)K + scol;
  const unsigned short* Bsrc = B + (bcol + srow) * (long)K + scol;
  const long hstep = (long)128 * K, lstep = (long)64 * K;

#define STAGE_A2(j, reg, h, L)                                                 \
  __builtin_amdgcn_global_load_lds(AS1(Asrc + (h)*hstep + (L)*lstep + (j)*64), \
      AS3(smem + (reg)*32768 + (h)*16384 + (L)*8192 + t * 16), 16, 0, 0)
#define STAGE_B2(j, L)                                                         \
  __builtin_amdgcn_global_load_lds(AS1(Bsrc + (L)*lstep + (j)*64),             \
      AS3(smem + 98304 + ((j)&1) * 16384 + (L)*8192 + t * 16), 16, 0, 0)

  const int xr = (fr & 7) << 4;
  const char* ArdRow = smem + (wr * 64 + fr) * 128;
  const char* BrdRow = smem + 98304 + (wc * 64 + fr) * 128;
#define RD_A2(ar_, m, kk) \
  (*(const s16x8*)(ArdRow + (ar_)*32768 + (m)*2048 + (((kk)*64 + fk * 16) ^ xr)))
#define RD_B2(pb_, n, kk) \
  (*(const s16x8*)(BrdRow + (pb_)*16384 + (n)*2048 + (((kk)*64 + fk * 16) ^ xr)))

  f32x4 acc[4][4];
#pragma unroll
  for (int m = 0; m < 4; m++)
#pragma unroll
    for (int n = 0; n < 4; n++) acc[m][n] = (f32x4)0.f;

  STAGE_A2(0, 0, 0, 0); STAGE_A2(0, 0, 0, 1); STAGE_A2(0, 0, 1, 0); STAGE_A2(0, 0, 1, 1);
  STAGE_B2(0, 0); STAGE_B2(0, 1);
  STAGE_A2(1, 1, 0, 0); STAGE_A2(1, 1, 0, 1); STAGE_A2(1, 1, 1, 0); STAGE_A2(1, 1, 1, 1);
  STAGE_B2(1, 0); STAGE_B2(1, 1);
  asm volatile("s_waitcnt vmcnt(6)" ::: "memory");
  __builtin_amdgcn_s_barrier();

  s16x8 bfr[4][2];
  s16x8 ap[2][2];
  ap[0][0] = RD_A2(0, 0, 0); ap[0][1] = RD_A2(0, 0, 1);

  int ar = 0;
  for (int g = 0; g < NT; ++g) {
    const int pb = g & 1;
    int sr = ar + 2; if (sr >= 3) sr -= 3;
    int nar = ar + 1; if (nar >= 3) nar = 0;
    const bool st = (g + 2 < NT);
#pragma unroll
    for (int p = 0; p < 4; ++p) {
      const int cs = p & 1, ns = cs ^ 1;
      if (p == 0) {
#pragma unroll
        for (int n = 0; n < 4; ++n) {
          bfr[n][0] = RD_B2(pb, n, 0);
          bfr[n][1] = RD_B2(pb, n, 1);
        }
      }
      asm volatile("s_waitcnt lgkmcnt(0)" ::: "memory");
      __builtin_amdgcn_sched_barrier(0);
      __builtin_amdgcn_s_setprio(1);
#pragma unroll
      for (int n = 0; n < 4; ++n) {
        acc[p][n] = __builtin_amdgcn_mfma_f32_16x16x32_bf16(
            ap[cs][0], bfr[n][0], acc[p][n], 0, 0, 0);
        acc[p][n] = __builtin_amdgcn_mfma_f32_16x16x32_bf16(
            ap[cs][1], bfr[n][1], acc[p][n], 0, 0, 0);
      }
      __builtin_amdgcn_s_setprio(0);
      if (p < 3) {
        ap[ns][0] = RD_A2(ar, p + 1, 0); ap[ns][1] = RD_A2(ar, p + 1, 1);
      } else if (g + 1 < NT) {
        ap[ns][0] = RD_A2(nar, 0, 0); ap[ns][1] = RD_A2(nar, 0, 1);
      }
      if (st) {
        if (p == 0) { STAGE_A2(g + 2, sr, 0, 0); STAGE_A2(g + 2, sr, 0, 1); }
        if (p == 1) { STAGE_A2(g + 2, sr, 1, 0); STAGE_A2(g + 2, sr, 1, 1); }
        if (p == 2) { STAGE_B2(g + 2, 0); STAGE_B2(g + 2, 1); }
      }
      if (p == 2 && g + 1 < NT) {
        if (st) asm volatile("s_waitcnt vmcnt(6)" ::: "memory");
        else    asm volatile("s_waitcnt vmcnt(0)" ::: "memory");
      }
      asm volatile("s_barrier" ::: "memory");
    }
    ar = nar;
  }

  float bi[4], ga[4], wl[4], bl[4];
#pragma unroll
  for (int n = 0; n < 4; ++n) {
    const long col = bcol + wc * 64 + n * 16 + fr;
    bi[n] = bias[col];
    ga[n] = gamma[col];
    wl[n] = w2l[col];
    bl[n] = b2l[col];
  }
  const long orow = brow + wr * 64 + fk * 4;
  const long ocol = bcol + wc * 64 + fr;
#pragma unroll
  for (int m = 0; m < 4; ++m)
#pragma unroll
    for (int r = 0; r < 4; ++r) {
      const long row = orow + m * 16 + r;
      const float mu = rowstats[row * 2];
      const float rs = rowstats[row * 2 + 1];
#pragma unroll
      for (int n = 0; n < 4; ++n) {
        const long col = ocol + n * 16;
        float v = rs * acc[m][n][r] - rs * mu * wl[n] + bl[n] + bi[n];
        Cf[row * (long)N + col] = v * ga[n] + resid[row * (long)N + col];
      }
    }
#undef STAGE_A2
#undef STAGE_B2
#undef RD_A2
#undef RD_B2
}

extern "C" void kernel_launch(void* const* d_in, const int* in_sizes, int n_in,
                              void* d_out, int out_size, void* d_ws, size_t ws_size,
                              hipStream_t stream) {
  const float* x     = (const float*)d_in[0];
  const float* W1    = (const float*)d_in[1];
  const float* b1    = (const float*)d_in[2];
  const float* ln_w  = (const float*)d_in[3];
  const float* ln_b  = (const float*)d_in[4];
  const float* W2    = (const float*)d_in[5];
  const float* b2    = (const float*)d_in[6];
  const float* gamma = (const float*)d_in[7];
  float* out = (float*)d_out;

  const int Nr = 8192, DIM = 1024, DFF = 4096, K1 = 3072;

  unsigned short* W1b  = (unsigned short*)d_ws;
  unsigned short* W2b  = W1b + (long)DFF * K1;
  unsigned short* h_in = W2b + (long)DIM * DFF;
  unsigned short* h_act = h_in + (long)Nr * K1;            // holds h' = relu(.)*lnw
  float* partial  = (float*)(h_act + (long)Nr * DFF);
  float* prefix   = partial + 128 * 1024;
  float* suffix   = prefix + 128 * 1024;
  float* pp       = suffix + 128 * 1024;                   // 32*16*256*2 = 262144
  float* rowstats = pp + 32 * 16 * 256 * 2;                // 8192*2
  float* w2l      = rowstats + (long)Nr * 2;               // 1024
  float* b2l      = w2l + DIM;                             // 1024

  hipFuncSetAttribute((const void*)gemm256_relu,
                      hipFuncAttributeMaxDynamicSharedMemorySize, 163840);
  hipFuncSetAttribute((const void*)gemm256_g2,
                      hipFuncAttributeMaxDynamicSharedMemorySize, 131072);

  cast2_bf16<<<2048, 256, 0, stream>>>(W1, W1b, (long)DFF * K1,
                                       W2, W2b, (long)DIM * DFF);

  scan_chunkmax<<<dim3(4, 128), 256, 0, stream>>>(x, partial);
  scan_chunkscan<<<4, 256, 0, stream>>>(partial, prefix, suffix);
  scan_emit<<<dim3(4, 128), 256, 0, stream>>>(x, prefix, suffix, h_in);

  w2_fold<<<DIM, 256, 0, stream>>>(W2, ln_w, ln_b, w2l, b2l);

  // GEMM1: h' = relu(h_in @ W1^T + b1)*lnw, + per-block LN stats partials
  gemm256_relu<<<512, 512, 163840, stream>>>(h_in, W1b, h_act, b1, ln_w, pp,
                                             Nr, DFF, K1);

  ln_stats_reduce<<<32, 256, 0, stream>>>(pp, rowstats);

  // GEMM2: out = (rs*(h'@W2^T) - rs*mu*w2l + b2l + b2)*gamma + x
  gemm256_g2<<<256, 512, 131072, stream>>>(h_act, W2b, out, b2, gamma, x,
                                           w2l, b2l, rowstats, Nr, DIM, DFF);
}

// Round 14
// 318.717 us; speedup vs baseline: 1.8997x; 1.0593x over previous
//
#include <hip/hip_runtime.h>

typedef __attribute__((ext_vector_type(4))) float f32x4;
typedef __attribute__((ext_vector_type(8))) short s16x8;
typedef __attribute__((ext_vector_type(8))) unsigned short u16x8;

#define AS1(p) ((const __attribute__((address_space(1))) void*)(p))
#define AS3(p) ((__attribute__((address_space(3))) void*)(p))

__device__ __forceinline__ unsigned short f2bf(float f) {
  unsigned u = __builtin_bit_cast(unsigned, f);
  u += 0x7fffu + ((u >> 16) & 1u);   // RNE; inputs are finite
  return (unsigned short)(u >> 16);
}
__device__ __forceinline__ float bf2f(unsigned short s) {
  unsigned u = ((unsigned)s) << 16;
  return __builtin_bit_cast(float, u);
}
// fp32 -> OCP e4m3fn (RNE, FTZ below 2^-6, clamp 448)
__device__ __forceinline__ unsigned f2e4m3(float f) {
  unsigned uf = __builtin_bit_cast(unsigned, f);
  unsigned s = (uf >> 24) & 0x80u;
  unsigned u = uf & 0x7fffffffu;
  if (u < 0x3c800000u) return s;
  if (u > 0x43e00000u) u = 0x43e00000u;
  u += 0x7ffffu + ((u >> 20) & 1u);
  unsigned v = (u >> 20) - 960u;
  if (v > 126u) v = 126u;
  return s | v;
}

// ---------------- weight casts: W1 -> fp8 (x32), W2 -> bf16, one launch ----------------
__global__ __launch_bounds__(256) void cast_weights(const float* __restrict__ W1,
                                                    unsigned char* __restrict__ W1q,
                                                    long n1,
                                                    const float* __restrict__ W2,
                                                    unsigned short* __restrict__ W2b,
                                                    long n2) {
  if (blockIdx.x < 1536) {
    long i = ((long)blockIdx.x * 256 + threadIdx.x) * 4;
    long stride = (long)1536 * 256 * 4;
    for (; i < n1; i += stride) {
      float4 f = *(const float4*)(W1 + i);
      unsigned v = f2e4m3(f.x * 32.f) | (f2e4m3(f.y * 32.f) << 8) |
                   (f2e4m3(f.z * 32.f) << 16) | (f2e4m3(f.w * 32.f) << 24);
      *(unsigned*)(W1q + i) = v;
    }
  } else {
    long i = ((long)(blockIdx.x - 1536) * 256 + threadIdx.x) * 4;
    long stride = (long)512 * 256 * 4;
    for (; i < n2; i += stride) {
      float4 f = *(const float4*)(W2 + i);
      ushort4 o = { f2bf(f.x), f2bf(f.y), f2bf(f.z), f2bf(f.w) };
      *(ushort4*)(W2b + i) = o;
    }
  }
}

// ---------------- LN fold: w2l = W2 @ lnw, b2l = W2 @ lnb ----------------
__global__ __launch_bounds__(256) void w2_fold(const float* __restrict__ W2,
                                               const float* __restrict__ lnw,
                                               const float* __restrict__ lnb,
                                               float* __restrict__ w2l,
                                               float* __restrict__ b2l) {
  const int n = blockIdx.x;
  const float* w = W2 + (long)n * 4096;
  float s = 0.f, b = 0.f;
  for (int k = threadIdx.x; k < 4096; k += 256) {
    float wv = w[k];
    s += wv * lnw[k];
    b += wv * lnb[k];
  }
#pragma unroll
  for (int off = 32; off; off >>= 1) {
    s += __shfl_xor(s, off, 64);
    b += __shfl_xor(b, off, 64);
  }
  __shared__ float ss[4], bb[4];
  const int wv2 = threadIdx.x >> 6;
  if ((threadIdx.x & 63) == 0) { ss[wv2] = s; bb[wv2] = b; }
  __syncthreads();
  if (threadIdx.x == 0) {
    w2l[n] = ss[0] + ss[1] + ss[2] + ss[3];
    b2l[n] = bb[0] + bb[1] + bb[2] + bb[3];
  }
}

// ---------------- hierarchical column cummax scan ----------------
__global__ __launch_bounds__(256) void scan_chunkmax(const float* __restrict__ x,
                                                     float* __restrict__ partial) {
  int col = blockIdx.x * 256 + threadIdx.x;
  int chunk = blockIdx.y;
  const float* p = x + (long)chunk * 64 * 1024 + col;
  float m = -INFINITY;
#pragma unroll 4
  for (int i = 0; i < 64; i++) m = fmaxf(m, p[(long)i * 1024]);
  partial[chunk * 1024 + col] = m;
}

__global__ __launch_bounds__(256) void scan_chunkscan(const float* __restrict__ partial,
                                                      float* __restrict__ prefix,
                                                      float* __restrict__ suffix) {
  int col = blockIdx.x * 256 + threadIdx.x;
  float v[128];
#pragma unroll
  for (int c = 0; c < 128; c++) v[c] = partial[c * 1024 + col];
  float run = -INFINITY;
#pragma unroll
  for (int c = 0; c < 128; c++) {
    prefix[c * 1024 + col] = run;
    run = fmaxf(run, v[c]);
  }
  run = -INFINITY;
#pragma unroll
  for (int c = 127; c >= 0; c--) {
    suffix[c * 1024 + col] = run;
    run = fmaxf(run, v[c]);
  }
}

// Emits h_in FP8 [8192, 3072]: x | before | after
__global__ __launch_bounds__(256) void scan_emit(const float* __restrict__ x,
                                                 const float* __restrict__ prefix,
                                                 const float* __restrict__ suffix,
                                                 unsigned char* __restrict__ h_in) {
  int col = blockIdx.x * 256 + threadIdx.x;
  int chunk = blockIdx.y;
  long r0 = (long)chunk * 64;
  float run = prefix[chunk * 1024 + col];
  for (int i = 0; i < 64; i++) {
    long row = r0 + i;
    float v = x[row * 1024 + col];
    unsigned char* hr = h_in + row * 3072;
    hr[col] = (unsigned char)f2e4m3(v);
    hr[1024 + col] = (unsigned char)(row == 0 ? 0u : f2e4m3(run));
    run = fmaxf(run, v);
  }
  float run2 = suffix[chunk * 1024 + col];
  for (int i = 63; i >= 0; i--) {
    long row = r0 + i;
    float v = x[row * 1024 + col];
    h_in[row * 3072 + 2048 + col] = (unsigned char)(row == 8191 ? 0u : f2e4m3(run2));
    run2 = fmaxf(run2, v);
  }
}

// ---------------- rowstats reducer ----------------
__global__ __launch_bounds__(256) void ln_stats_reduce(const float* __restrict__ pp,
                                                       float* __restrict__ rowstats) {
  int row = blockIdx.x * 256 + threadIdx.x;
  int tm = row >> 8, rl = row & 255;
  float s = 0.f, q = 0.f;
#pragma unroll
  for (int tn = 0; tn < 16; ++tn) {
    const float* p = pp + (((long)(tm * 16 + tn) * 256 + rl) * 2);
    s += p[0];
    q += p[1];
  }
  float mu = s * (1.f / 4096.f);
  float var = q * (1.f / 4096.f) - mu * mu;
  rowstats[row * 2] = mu;
  rowstats[row * 2 + 1] = rsqrtf(var + 1e-6f);
}

// ============ 256x256 FP8 GEMM1, BK=128 (r14): h' = relu(A@B^T/32 + b1)*lnw, + LN stats ============
// fp8 rows at BK=128 are 128 B — byte-identical geometry to the verified bf16
// BK=64 layout: same staging map + 3-bit (fr&7)<<4 swizzle + r12 sync skeleton
// (8 loads/tile, vmcnt(8) prologue, vmcnt(6|0) at p2). Frag reads are b64 at
// (kk*32+fk*8)^xr, kk 0..3; bank check: slot = fk^2*(fr&7) covers all 16 8-B
// slots x4 lanes = 2 lanes/bank = free. NT = K/128 = 24 (half the barriers/K).
__global__ __launch_bounds__(512, 2) void gemm256_relu(
    const unsigned char* __restrict__ A, const unsigned char* __restrict__ B,
    unsigned short* __restrict__ C, const float* __restrict__ bias,
    const float* __restrict__ lnw, float* __restrict__ pp,
    int M, int N, int K) {
  extern __shared__ char smem[];
  const int NT = K >> 7;  // 128-elem (=128 B) K-tiles

  const int nwg = gridDim.x;
  const int cpx = nwg >> 3;
  const int bid = blockIdx.x;
  const int swz = (bid & 7) * cpx + (bid >> 3);
  const int tiles_m = M >> 8;
  const int tm = swz % tiles_m;
  const int tn = swz / tiles_m;
  const long brow = (long)tm * 256;
  const long bcol = (long)tn * 256;

  const int t = threadIdx.x;
  const int lane = t & 63, wv = t >> 6;
  const int wr = wv >> 2, wc = wv & 3;
  const int fr = lane & 15, fk = lane >> 4;

  // staging: row = t>>3 (+64L +128h), phys byte col (t&7)*16; inverse swizzle
  const int srow = t >> 3;
  const int scol = ((t & 7) * 16) ^ (((t >> 3) & 7) << 4);  // BYTES
  const unsigned char* Asrc = A + (brow + srow) * (long)K + scol;
  const unsigned char* Bsrc = B + (bcol + srow) * (long)K + scol;
  const long hstep = (long)128 * K, lstep = (long)64 * K;

#define STAGE_A(j, reg, h, L)                                                   \
  __builtin_amdgcn_global_load_lds(AS1(Asrc + (h)*hstep + (L)*lstep + (j)*128), \
      AS3(smem + (reg)*32768 + (h)*16384 + (L)*8192 + t * 16), 16, 0, 0)
#define STAGE_B(j, h, L)                                                        \
  __builtin_amdgcn_global_load_lds(AS1(Bsrc + (h)*hstep + (L)*lstep + (j)*128), \
      AS3(smem + 98304 + ((j)&1) * 32768 + (h)*16384 + (L)*8192 + t * 16), 16, 0, 0)

  const int xr = (fr & 7) << 4;
  const char* ArdRow = smem + (wr * 128 + fr) * 128;
  const char* BrdRow = smem + 98304 + (wc * 64 + fr) * 128;
#define RD_A(ar_, m, kk) \
  (*(const long*)(ArdRow + (ar_)*32768 + (m)*2048 + (((kk)*32 + fk * 8) ^ xr)))
#define RD_B(pb_, n, kk) \
  (*(const long*)(BrdRow + (pb_)*32768 + (n)*2048 + (((kk)*32 + fk * 8) ^ xr)))

#define MFMA_QUAD(mi, a_)                                                      \
  _Pragma("unroll")                                                            \
  for (int n = 0; n < 4; ++n) {                                                \
    _Pragma("unroll")                                                          \
    for (int kk = 0; kk < 4; ++kk)                                             \
      acc[(mi)][n] = __builtin_amdgcn_mfma_f32_16x16x32_fp8_fp8(               \
          a_[kk], bfr[n][kk], acc[(mi)][n], 0, 0, 0);                          \
  }

  f32x4 acc[8][4];
#pragma unroll
  for (int m = 0; m < 8; m++)
#pragma unroll
    for (int n = 0; n < 4; n++) acc[m][n] = (f32x4)0.f;

  // prologue: tile0 (A,B), tile1 (A,B) = 16 loads; vmcnt(8) lands tile0's 8
  STAGE_A(0, 0, 0, 0); STAGE_A(0, 0, 0, 1); STAGE_A(0, 0, 1, 0); STAGE_A(0, 0, 1, 1);
  STAGE_B(0, 0, 0); STAGE_B(0, 0, 1); STAGE_B(0, 1, 0); STAGE_B(0, 1, 1);
  STAGE_A(1, 1, 0, 0); STAGE_A(1, 1, 0, 1); STAGE_A(1, 1, 1, 0); STAGE_A(1, 1, 1, 1);
  STAGE_B(1, 0, 0); STAGE_B(1, 0, 1); STAGE_B(1, 1, 0); STAGE_B(1, 1, 1);
  asm volatile("s_waitcnt vmcnt(8)" ::: "memory");
  __builtin_amdgcn_s_barrier();

  long bfr[4][4];
  long ap[2][2][4];  // [set][i][kk]
  ap[0][0][0] = RD_A(0, 0, 0); ap[0][0][1] = RD_A(0, 0, 1);
  ap[0][0][2] = RD_A(0, 0, 2); ap[0][0][3] = RD_A(0, 0, 3);
  ap[0][1][0] = RD_A(0, 1, 0); ap[0][1][1] = RD_A(0, 1, 1);
  ap[0][1][2] = RD_A(0, 1, 2); ap[0][1][3] = RD_A(0, 1, 3);

  int ar = 0;
  for (int g = 0; g < NT; ++g) {
    const int pb = g & 1;
    int sr = ar + 2; if (sr >= 3) sr -= 3;
    int nar = ar + 1; if (nar >= 3) nar = 0;
    const bool st = (g + 2 < NT);
#pragma unroll
    for (int p = 0; p < 4; ++p) {
      const int cs = p & 1, ns = cs ^ 1;
      if (p == 0) {
#pragma unroll
        for (int n = 0; n < 4; ++n)
#pragma unroll
          for (int kk = 0; kk < 4; ++kk) bfr[n][kk] = RD_B(pb, n, kk);
      }
      asm volatile("s_waitcnt lgkmcnt(0)" ::: "memory");
      __builtin_amdgcn_sched_barrier(0);
      __builtin_amdgcn_s_setprio(1);
      MFMA_QUAD(2 * p, ap[cs][0])
      MFMA_QUAD(2 * p + 1, ap[cs][1])
      __builtin_amdgcn_s_setprio(0);
      if (p < 3) {
#pragma unroll
        for (int kk = 0; kk < 4; ++kk) {
          ap[ns][0][kk] = RD_A(ar, 2 * p + 2, kk);
          ap[ns][1][kk] = RD_A(ar, 2 * p + 3, kk);
        }
      } else if (g + 1 < NT) {
#pragma unroll
        for (int kk = 0; kk < 4; ++kk) {
          ap[ns][0][kk] = RD_A(nar, 0, kk);
          ap[ns][1][kk] = RD_A(nar, 1, kk);
        }
      }
      if (st) {
        if (p == 0) { STAGE_A(g + 2, sr, 0, 0); STAGE_A(g + 2, sr, 0, 1); }
        if (p == 1) { STAGE_A(g + 2, sr, 1, 0); STAGE_A(g + 2, sr, 1, 1); }
        if (p == 2) { STAGE_B(g + 2, 0, 0); STAGE_B(g + 2, 0, 1); }
        if (p == 3) { STAGE_B(g + 2, 1, 0); STAGE_B(g + 2, 1, 1); }
      }
      if (p == 2 && g + 1 < NT) {
        if (st) asm volatile("s_waitcnt vmcnt(6)" ::: "memory");
        else    asm volatile("s_waitcnt vmcnt(0)" ::: "memory");
      }
      asm volatile("s_barrier" ::: "memory");
    }
    ar = nar;
  }

  // ---- fused epilogue: v = acc/32 + b1; h' = relu(v)*lnw; LN stat partials ----
  float bi[4], lw[4];
#pragma unroll
  for (int n = 0; n < 4; ++n) {
    const long col = bcol + wc * 64 + n * 16 + fr;
    bi[n] = bias[col];
    lw[n] = lnw[col];
  }
  float* sred = (float*)smem;
  float* qred = sred + 1024;
  const long orow = brow + wr * 128 + fk * 4;
  const long ocol = bcol + wc * 64 + fr;
#pragma unroll
  for (int m = 0; m < 8; ++m) {
#pragma unroll
    for (int r = 0; r < 4; ++r) {
      const long row = orow + m * 16 + r;
      float s = 0.f, q = 0.f;
#pragma unroll
      for (int n = 0; n < 4; ++n) {
        float v = acc[m][n][r] * 0.03125f + bi[n];
        v = v > 0.f ? v : 0.f;
        s += v;
        q += v * v;
        C[row * (long)N + ocol + n * 16] = f2bf(v * lw[n]);
      }
#pragma unroll
      for (int off = 1; off < 16; off <<= 1) {
        s += __shfl_xor(s, off, 64);
        q += __shfl_xor(q, off, 64);
      }
      if (fr == 0) {
        int rl = wr * 128 + m * 16 + fk * 4 + r;
        sred[rl * 4 + wc] = s;
        qred[rl * 4 + wc] = q;
      }
    }
  }
  __syncthreads();
  if (t < 256) {
    float s = sred[t * 4] + sred[t * 4 + 1] + sred[t * 4 + 2] + sred[t * 4 + 3];
    float q = qred[t * 4] + qred[t * 4 + 1] + qred[t * 4 + 2] + qred[t * 4 + 3];
    float* pb = pp + (((long)(tm * 16 + tn) * 256 + t) * 2);
    pb[0] = s;
    pb[1] = q;
  }
#undef STAGE_A
#undef STAGE_B
#undef RD_A
#undef RD_B
#undef MFMA_QUAD
}

// ============ 256x128-tile bf16 GEMM2 (r13): out = (rs*G - rs*mu*w2l + b2l + b2)*gamma + x ============
__global__ __launch_bounds__(512, 2) void gemm256_g2(
    const unsigned short* __restrict__ A, const unsigned short* __restrict__ B,
    float* __restrict__ Cf, const float* __restrict__ bias,
    const float* __restrict__ gamma, const float* __restrict__ resid,
    const float* __restrict__ w2l, const float* __restrict__ b2l,
    const float* __restrict__ rowstats,
    int M, int N, int K) {
  extern __shared__ char smem[];
  const int NT = K >> 6;

  const int nwg = gridDim.x;
  const int cpx = nwg >> 3;
  const int bid = blockIdx.x;
  const int swz = (bid & 7) * cpx + (bid >> 3);
  const int tiles_m = M >> 8;
  const int tm = swz % tiles_m;
  const int tn = swz / tiles_m;
  const long brow = (long)tm * 256;
  const long bcol = (long)tn * 128;

  const int t = threadIdx.x;
  const int lane = t & 63, wv = t >> 6;
  const int wr = wv >> 1, wc = wv & 1;
  const int fr = lane & 15, fk = lane >> 4;

  const int srow = t >> 3;
  const int scol = 8 * ((t & 7) ^ ((t >> 3) & 7));
  const unsigned short* Asrc = A + (brow + srow) * (long)K + scol;
  const unsigned short* Bsrc = B + (bcol + srow) * (long)K + scol;
  const long hstep = (long)128 * K, lstep = (long)64 * K;

#define STAGE_A2(j, reg, h, L)                                                 \
  __builtin_amdgcn_global_load_lds(AS1(Asrc + (h)*hstep + (L)*lstep + (j)*64), \
      AS3(smem + (reg)*32768 + (h)*16384 + (L)*8192 + t * 16), 16, 0, 0)
#define STAGE_B2(j, L)                                                         \
  __builtin_amdgcn_global_load_lds(AS1(Bsrc + (L)*lstep + (j)*64),             \
      AS3(smem + 98304 + ((j)&1) * 16384 + (L)*8192 + t * 16), 16, 0, 0)

  const int xr = (fr & 7) << 4;
  const char* ArdRow = smem + (wr * 64 + fr) * 128;
  const char* BrdRow = smem + 98304 + (wc * 64 + fr) * 128;
#define RD_A2(ar_, m, kk) \
  (*(const s16x8*)(ArdRow + (ar_)*32768 + (m)*2048 + (((kk)*64 + fk * 16) ^ xr)))
#define RD_B2(pb_, n, kk) \
  (*(const s16x8*)(BrdRow + (pb_)*16384 + (n)*2048 + (((kk)*64 + fk * 16) ^ xr)))

  f32x4 acc[4][4];
#pragma unroll
  for (int m = 0; m < 4; m++)
#pragma unroll
    for (int n = 0; n < 4; n++) acc[m][n] = (f32x4)0.f;

  STAGE_A2(0, 0, 0, 0); STAGE_A2(0, 0, 0, 1); STAGE_A2(0, 0, 1, 0); STAGE_A2(0, 0, 1, 1);
  STAGE_B2(0, 0); STAGE_B2(0, 1);
  STAGE_A2(1, 1, 0, 0); STAGE_A2(1, 1, 0, 1); STAGE_A2(1, 1, 1, 0); STAGE_A2(1, 1, 1, 1);
  STAGE_B2(1, 0); STAGE_B2(1, 1);
  asm volatile("s_waitcnt vmcnt(6)" ::: "memory");
  __builtin_amdgcn_s_barrier();

  s16x8 bfr[4][2];
  s16x8 ap[2][2];
  ap[0][0] = RD_A2(0, 0, 0); ap[0][1] = RD_A2(0, 0, 1);

  int ar = 0;
  for (int g = 0; g < NT; ++g) {
    const int pb = g & 1;
    int sr = ar + 2; if (sr >= 3) sr -= 3;
    int nar = ar + 1; if (nar >= 3) nar = 0;
    const bool st = (g + 2 < NT);
#pragma unroll
    for (int p = 0; p < 4; ++p) {
      const int cs = p & 1, ns = cs ^ 1;
      if (p == 0) {
#pragma unroll
        for (int n = 0; n < 4; ++n) {
          bfr[n][0] = RD_B2(pb, n, 0);
          bfr[n][1] = RD_B2(pb, n, 1);
        }
      }
      asm volatile("s_waitcnt lgkmcnt(0)" ::: "memory");
      __builtin_amdgcn_sched_barrier(0);
      __builtin_amdgcn_s_setprio(1);
#pragma unroll
      for (int n = 0; n < 4; ++n) {
        acc[p][n] = __builtin_amdgcn_mfma_f32_16x16x32_bf16(
            ap[cs][0], bfr[n][0], acc[p][n], 0, 0, 0);
        acc[p][n] = __builtin_amdgcn_mfma_f32_16x16x32_bf16(
            ap[cs][1], bfr[n][1], acc[p][n], 0, 0, 0);
      }
      __builtin_amdgcn_s_setprio(0);
      if (p < 3) {
        ap[ns][0] = RD_A2(ar, p + 1, 0); ap[ns][1] = RD_A2(ar, p + 1, 1);
      } else if (g + 1 < NT) {
        ap[ns][0] = RD_A2(nar, 0, 0); ap[ns][1] = RD_A2(nar, 0, 1);
      }
      if (st) {
        if (p == 0) { STAGE_A2(g + 2, sr, 0, 0); STAGE_A2(g + 2, sr, 0, 1); }
        if (p == 1) { STAGE_A2(g + 2, sr, 1, 0); STAGE_A2(g + 2, sr, 1, 1); }
        if (p == 2) { STAGE_B2(g + 2, 0); STAGE_B2(g + 2, 1); }
      }
      if (p == 2 && g + 1 < NT) {
        if (st) asm volatile("s_waitcnt vmcnt(6)" ::: "memory");
        else    asm volatile("s_waitcnt vmcnt(0)" ::: "memory");
      }
      asm volatile("s_barrier" ::: "memory");
    }
    ar = nar;
  }

  float bi[4], ga[4], wl[4], bl[4];
#pragma unroll
  for (int n = 0; n < 4; ++n) {
    const long col = bcol + wc * 64 + n * 16 + fr;
    bi[n] = bias[col];
    ga[n] = gamma[col];
    wl[n] = w2l[col];
    bl[n] = b2l[col];
  }
  const long orow = brow + wr * 64 + fk * 4;
  const long ocol = bcol + wc * 64 + fr;
#pragma unroll
  for (int m = 0; m < 4; ++m)
#pragma unroll
    for (int r = 0; r < 4; ++r) {
      const long row = orow + m * 16 + r;
      const float mu = rowstats[row * 2];
      const float rs = rowstats[row * 2 + 1];
#pragma unroll
      for (int n = 0; n < 4; ++n) {
        const long col = ocol + n * 16;
        float v = rs * acc[m][n][r] - rs * mu * wl[n] + bl[n] + bi[n];
        Cf[row * (long)N + col] = v * ga[n] + resid[row * (long)N + col];
      }
    }
#undef STAGE_A2
#undef STAGE_B2
#undef RD_A2
#undef RD_B2
}

extern "C" void kernel_launch(void* const* d_in, const int* in_sizes, int n_in,
                              void* d_out, int out_size, void* d_ws, size_t ws_size,
                              hipStream_t stream) {
  const float* x     = (const float*)d_in[0];
  const float* W1    = (const float*)d_in[1];
  const float* b1    = (const float*)d_in[2];
  const float* ln_w  = (const float*)d_in[3];
  const float* ln_b  = (const float*)d_in[4];
  const float* W2    = (const float*)d_in[5];
  const float* b2    = (const float*)d_in[6];
  const float* gamma = (const float*)d_in[7];
  float* out = (float*)d_out;

  const int Nr = 8192, DIM = 1024, DFF = 4096, K1 = 3072;

  unsigned char* W1q    = (unsigned char*)d_ws;            // 12.58 MB fp8
  unsigned short* W2b   = (unsigned short*)(W1q + (long)DFF * K1);
  unsigned char* h_in   = (unsigned char*)(W2b + (long)DIM * DFF);  // 25.2 MB fp8
  unsigned short* h_act = (unsigned short*)(h_in + (long)Nr * K1);  // 67 MB bf16
  float* partial  = (float*)(h_act + (long)Nr * DFF);
  float* prefix   = partial + 128 * 1024;
  float* suffix   = prefix + 128 * 1024;
  float* pp       = suffix + 128 * 1024;
  float* rowstats = pp + 32 * 16 * 256 * 2;
  float* w2l      = rowstats + (long)Nr * 2;
  float* b2l      = w2l + DIM;

  hipFuncSetAttribute((const void*)gemm256_relu,
                      hipFuncAttributeMaxDynamicSharedMemorySize, 163840);
  hipFuncSetAttribute((const void*)gemm256_g2,
                      hipFuncAttributeMaxDynamicSharedMemorySize, 131072);

  cast_weights<<<2048, 256, 0, stream>>>(W1, W1q, (long)DFF * K1,
                                         W2, W2b, (long)DIM * DFF);

  scan_chunkmax<<<dim3(4, 128), 256, 0, stream>>>(x, partial);
  scan_chunkscan<<<4, 256, 0, stream>>>(partial, prefix, suffix);
  scan_emit<<<dim3(4, 128), 256, 0, stream>>>(x, prefix, suffix, h_in);

  w2_fold<<<DIM, 256, 0, stream>>>(W2, ln_w, ln_b, w2l, b2l);

  // GEMM1 (fp8, BK=128): h' = relu(h_in @ W1q^T / 32 + b1)*lnw, + LN stat partials
  gemm256_relu<<<512, 512, 163840, stream>>>(h_in, W1q, h_act, b1, ln_w, pp,
                                             Nr, DFF, K1);

  ln_stats_reduce<<<32, 256, 0, stream>>>(pp, rowstats);

  // GEMM2 (bf16): out = (rs*(h'@W2^T) - rs*mu*w2l + b2l + b2)*gamma + x
  gemm256_g2<<<256, 512, 131072, stream>>>(h_act, W2b, out, b2, gamma, x,
                                           w2l, b2l, rowstats, Nr, DIM, DFF);
}

// Round 15
// 315.020 us; speedup vs baseline: 1.9220x; 1.0117x over previous
//
#include <hip/hip_runtime.h>

typedef __attribute__((ext_vector_type(4))) float f32x4;
typedef __attribute__((ext_vector_type(8))) short s16x8;
typedef __attribute__((ext_vector_type(8))) unsigned short u16x8;

#define AS1(p) ((const __attribute__((address_space(1))) void*)(p))
#define AS3(p) ((__attribute__((address_space(3))) void*)(p))

__device__ __forceinline__ unsigned short f2bf(float f) {
  unsigned u = __builtin_bit_cast(unsigned, f);
  u += 0x7fffu + ((u >> 16) & 1u);   // RNE; inputs are finite
  return (unsigned short)(u >> 16);
}
__device__ __forceinline__ float bf2f(unsigned short s) {
  unsigned u = ((unsigned)s) << 16;
  return __builtin_bit_cast(float, u);
}
// fp32 -> OCP e4m3fn (RNE, FTZ below 2^-6, clamp 448)
__device__ __forceinline__ unsigned f2e4m3(float f) {
  unsigned uf = __builtin_bit_cast(unsigned, f);
  unsigned s = (uf >> 24) & 0x80u;
  unsigned u = uf & 0x7fffffffu;
  if (u < 0x3c800000u) return s;
  if (u > 0x43e00000u) u = 0x43e00000u;
  u += 0x7ffffu + ((u >> 20) & 1u);
  unsigned v = (u >> 20) - 960u;
  if (v > 126u) v = 126u;
  return s | v;
}

// r15 global pre-swizzle for fp8 GEMM1 operands (producers write it; GEMM1
// stages LINEARLY and reads with xr = fr<<3):
//   phys_k = (k & ~127) | ((k & 127) ^ ((row & 15) << 3))
// b64-read slot = (kk*4+fk) ^ fr: each 16-lane phase covers all 16 8-B slots
// exactly once = conflict-free (r14's 2-bit XOR left slot-bit0 constant ->
// measured 1.9e7 = 2x LDS-read time).

// ---------------- weight casts: W1 -> fp8 (x32, pre-swizzled), W2 -> bf16 ----------------
__global__ __launch_bounds__(256) void cast_weights(const float* __restrict__ W1,
                                                    unsigned char* __restrict__ W1q,
                                                    long n1,
                                                    const float* __restrict__ W2,
                                                    unsigned short* __restrict__ W2b,
                                                    long n2) {
  if (blockIdx.x < 1536) {
    long i = ((long)blockIdx.x * 256 + threadIdx.x) * 4;
    long stride = (long)1536 * 256 * 4;
    for (; i < n1; i += stride) {
      float4 f = *(const float4*)(W1 + i);
      unsigned v = f2e4m3(f.x * 32.f) | (f2e4m3(f.y * 32.f) << 8) |
                   (f2e4m3(f.z * 32.f) << 16) | (f2e4m3(f.w * 32.f) << 24);
      long n = i / 3072;
      long k = i - n * 3072;
      long phys = n * 3072 + (k & ~(long)127) + ((k & 127) ^ ((n & 15) << 3));
      *(unsigned*)(W1q + phys) = v;
    }
  } else {
    long i = ((long)(blockIdx.x - 1536) * 256 + threadIdx.x) * 4;
    long stride = (long)512 * 256 * 4;
    for (; i < n2; i += stride) {
      float4 f = *(const float4*)(W2 + i);
      ushort4 o = { f2bf(f.x), f2bf(f.y), f2bf(f.z), f2bf(f.w) };
      *(ushort4*)(W2b + i) = o;
    }
  }
}

// ---------------- LN fold: w2l = W2 @ lnw, b2l = W2 @ lnb ----------------
__global__ __launch_bounds__(256) void w2_fold(const float* __restrict__ W2,
                                               const float* __restrict__ lnw,
                                               const float* __restrict__ lnb,
                                               float* __restrict__ w2l,
                                               float* __restrict__ b2l) {
  const int n = blockIdx.x;
  const float* w = W2 + (long)n * 4096;
  float s = 0.f, b = 0.f;
  for (int k = threadIdx.x; k < 4096; k += 256) {
    float wv = w[k];
    s += wv * lnw[k];
    b += wv * lnb[k];
  }
#pragma unroll
  for (int off = 32; off; off >>= 1) {
    s += __shfl_xor(s, off, 64);
    b += __shfl_xor(b, off, 64);
  }
  __shared__ float ss[4], bb[4];
  const int wv2 = threadIdx.x >> 6;
  if ((threadIdx.x & 63) == 0) { ss[wv2] = s; bb[wv2] = b; }
  __syncthreads();
  if (threadIdx.x == 0) {
    w2l[n] = ss[0] + ss[1] + ss[2] + ss[3];
    b2l[n] = bb[0] + bb[1] + bb[2] + bb[3];
  }
}

// ---------------- hierarchical column cummax scan ----------------
__global__ __launch_bounds__(256) void scan_chunkmax(const float* __restrict__ x,
                                                     float* __restrict__ partial) {
  int col = blockIdx.x * 256 + threadIdx.x;
  int chunk = blockIdx.y;
  const float* p = x + (long)chunk * 64 * 1024 + col;
  float m = -INFINITY;
#pragma unroll 4
  for (int i = 0; i < 64; i++) m = fmaxf(m, p[(long)i * 1024]);
  partial[chunk * 1024 + col] = m;
}

__global__ __launch_bounds__(256) void scan_chunkscan(const float* __restrict__ partial,
                                                      float* __restrict__ prefix,
                                                      float* __restrict__ suffix) {
  int col = blockIdx.x * 256 + threadIdx.x;
  float v[128];
#pragma unroll
  for (int c = 0; c < 128; c++) v[c] = partial[c * 1024 + col];
  float run = -INFINITY;
#pragma unroll
  for (int c = 0; c < 128; c++) {
    prefix[c * 1024 + col] = run;
    run = fmaxf(run, v[c]);
  }
  run = -INFINITY;
#pragma unroll
  for (int c = 127; c >= 0; c--) {
    suffix[c * 1024 + col] = run;
    run = fmaxf(run, v[c]);
  }
}

// Emits h_in FP8 [8192, 3072] (x | before | after), PRE-SWIZZLED per r15 rule.
__global__ __launch_bounds__(256) void scan_emit(const float* __restrict__ x,
                                                 const float* __restrict__ prefix,
                                                 const float* __restrict__ suffix,
                                                 unsigned char* __restrict__ h_in) {
  int col = blockIdx.x * 256 + threadIdx.x;   // 0..1023
  int chunk = blockIdx.y;
  long r0 = (long)chunk * 64;
  const int cb = col & ~127, cw = col & 127;
  float run = prefix[chunk * 1024 + col];
  for (int i = 0; i < 64; i++) {
    long row = r0 + i;
    int xo = (int)(row & 15) << 3;
    int c0 = cb | (cw ^ xo);
    float v = x[row * 1024 + col];
    unsigned char* hr = h_in + row * 3072;
    hr[c0] = (unsigned char)f2e4m3(v);
    hr[1024 + c0] = (unsigned char)(row == 0 ? 0u : f2e4m3(run));
    run = fmaxf(run, v);
  }
  float run2 = suffix[chunk * 1024 + col];
  for (int i = 63; i >= 0; i--) {
    long row = r0 + i;
    int xo = (int)(row & 15) << 3;
    int c0 = cb | (cw ^ xo);
    float v = x[row * 1024 + col];
    h_in[row * 3072 + 2048 + c0] = (unsigned char)(row == 8191 ? 0u : f2e4m3(run2));
    run2 = fmaxf(run2, v);
  }
}

// ---------------- rowstats reducer ----------------
__global__ __launch_bounds__(256) void ln_stats_reduce(const float* __restrict__ pp,
                                                       float* __restrict__ rowstats) {
  int row = blockIdx.x * 256 + threadIdx.x;
  int tm = row >> 8, rl = row & 255;
  float s = 0.f, q = 0.f;
#pragma unroll
  for (int tn = 0; tn < 16; ++tn) {
    const float* p = pp + (((long)(tm * 16 + tn) * 256 + rl) * 2);
    s += p[0];
    q += p[1];
  }
  float mu = s * (1.f / 4096.f);
  float var = q * (1.f / 4096.f) - mu * mu;
  rowstats[row * 2] = mu;
  rowstats[row * 2 + 1] = rsqrtf(var + 1e-6f);
}

// ============ 256x256 FP8 GEMM1, BK=128 (r15): h' = relu(A@B^T/32 + b1)*lnw, + LN stats ============
// Operands pre-swizzled in GLOBAL memory (producers above) -> staging is a pure
// linear copy; b64 reads use xr = fr<<3 (full 4-bit row XOR, conflict-free at
// every 16-lane phase). Sync skeleton identical to r12-r14 (verified).
__global__ __launch_bounds__(512, 2) void gemm256_relu(
    const unsigned char* __restrict__ A, const unsigned char* __restrict__ B,
    unsigned short* __restrict__ C, const float* __restrict__ bias,
    const float* __restrict__ lnw, float* __restrict__ pp,
    int M, int N, int K) {
  extern __shared__ char smem[];
  const int NT = K >> 7;  // 128-B K-tiles

  const int nwg = gridDim.x;
  const int cpx = nwg >> 3;
  const int bid = blockIdx.x;
  const int swz = (bid & 7) * cpx + (bid >> 3);
  const int tiles_m = M >> 8;
  const int tm = swz % tiles_m;
  const int tn = swz / tiles_m;
  const long brow = (long)tm * 256;
  const long bcol = (long)tn * 256;

  const int t = threadIdx.x;
  const int lane = t & 63, wv = t >> 6;
  const int wr = wv >> 2, wc = wv & 3;
  const int fr = lane & 15, fk = lane >> 4;

  // staging: pure linear copy (global already holds the swizzled image)
  const int srow = t >> 3;
  const int scol = (t & 7) * 16;  // bytes
  const unsigned char* Asrc = A + (brow + srow) * (long)K + scol;
  const unsigned char* Bsrc = B + (bcol + srow) * (long)K + scol;
  const long hstep = (long)128 * K, lstep = (long)64 * K;

#define STAGE_A(j, reg, h, L)                                                   \
  __builtin_amdgcn_global_load_lds(AS1(Asrc + (h)*hstep + (L)*lstep + (j)*128), \
      AS3(smem + (reg)*32768 + (h)*16384 + (L)*8192 + t * 16), 16, 0, 0)
#define STAGE_B(j, h, L)                                                        \
  __builtin_amdgcn_global_load_lds(AS1(Bsrc + (h)*hstep + (L)*lstep + (j)*128), \
      AS3(smem + 98304 + ((j)&1) * 32768 + (h)*16384 + (L)*8192 + t * 16), 16, 0, 0)

  const int xr = fr << 3;  // row&15 = fr for all frag rows
  const char* ArdRow = smem + (wr * 128 + fr) * 128;
  const char* BrdRow = smem + 98304 + (wc * 64 + fr) * 128;
#define RD_A(ar_, m, kk) \
  (*(const long*)(ArdRow + (ar_)*32768 + (m)*2048 + (((kk)*32 + fk * 8) ^ xr)))
#define RD_B(pb_, n, kk) \
  (*(const long*)(BrdRow + (pb_)*32768 + (n)*2048 + (((kk)*32 + fk * 8) ^ xr)))

#define MFMA_QUAD(mi, a_)                                                      \
  _Pragma("unroll")                                                            \
  for (int n = 0; n < 4; ++n) {                                                \
    _Pragma("unroll")                                                          \
    for (int kk = 0; kk < 4; ++kk)                                             \
      acc[(mi)][n] = __builtin_amdgcn_mfma_f32_16x16x32_fp8_fp8(               \
          a_[kk], bfr[n][kk], acc[(mi)][n], 0, 0, 0);                          \
  }

  f32x4 acc[8][4];
#pragma unroll
  for (int m = 0; m < 8; m++)
#pragma unroll
    for (int n = 0; n < 4; n++) acc[m][n] = (f32x4)0.f;

  STAGE_A(0, 0, 0, 0); STAGE_A(0, 0, 0, 1); STAGE_A(0, 0, 1, 0); STAGE_A(0, 0, 1, 1);
  STAGE_B(0, 0, 0); STAGE_B(0, 0, 1); STAGE_B(0, 1, 0); STAGE_B(0, 1, 1);
  STAGE_A(1, 1, 0, 0); STAGE_A(1, 1, 0, 1); STAGE_A(1, 1, 1, 0); STAGE_A(1, 1, 1, 1);
  STAGE_B(1, 0, 0); STAGE_B(1, 0, 1); STAGE_B(1, 1, 0); STAGE_B(1, 1, 1);
  asm volatile("s_waitcnt vmcnt(8)" ::: "memory");
  __builtin_amdgcn_s_barrier();

  long bfr[4][4];
  long ap[2][2][4];
  ap[0][0][0] = RD_A(0, 0, 0); ap[0][0][1] = RD_A(0, 0, 1);
  ap[0][0][2] = RD_A(0, 0, 2); ap[0][0][3] = RD_A(0, 0, 3);
  ap[0][1][0] = RD_A(0, 1, 0); ap[0][1][1] = RD_A(0, 1, 1);
  ap[0][1][2] = RD_A(0, 1, 2); ap[0][1][3] = RD_A(0, 1, 3);

  int ar = 0;
  for (int g = 0; g < NT; ++g) {
    const int pb = g & 1;
    int sr = ar + 2; if (sr >= 3) sr -= 3;
    int nar = ar + 1; if (nar >= 3) nar = 0;
    const bool st = (g + 2 < NT);
#pragma unroll
    for (int p = 0; p < 4; ++p) {
      const int cs = p & 1, ns = cs ^ 1;
      if (p == 0) {
#pragma unroll
        for (int n = 0; n < 4; ++n)
#pragma unroll
          for (int kk = 0; kk < 4; ++kk) bfr[n][kk] = RD_B(pb, n, kk);
      }
      asm volatile("s_waitcnt lgkmcnt(0)" ::: "memory");
      __builtin_amdgcn_sched_barrier(0);
      __builtin_amdgcn_s_setprio(1);
      MFMA_QUAD(2 * p, ap[cs][0])
      MFMA_QUAD(2 * p + 1, ap[cs][1])
      __builtin_amdgcn_s_setprio(0);
      if (p < 3) {
#pragma unroll
        for (int kk = 0; kk < 4; ++kk) {
          ap[ns][0][kk] = RD_A(ar, 2 * p + 2, kk);
          ap[ns][1][kk] = RD_A(ar, 2 * p + 3, kk);
        }
      } else if (g + 1 < NT) {
#pragma unroll
        for (int kk = 0; kk < 4; ++kk) {
          ap[ns][0][kk] = RD_A(nar, 0, kk);
          ap[ns][1][kk] = RD_A(nar, 1, kk);
        }
      }
      if (st) {
        if (p == 0) { STAGE_A(g + 2, sr, 0, 0); STAGE_A(g + 2, sr, 0, 1); }
        if (p == 1) { STAGE_A(g + 2, sr, 1, 0); STAGE_A(g + 2, sr, 1, 1); }
        if (p == 2) { STAGE_B(g + 2, 0, 0); STAGE_B(g + 2, 0, 1); }
        if (p == 3) { STAGE_B(g + 2, 1, 0); STAGE_B(g + 2, 1, 1); }
      }
      if (p == 2 && g + 1 < NT) {
        if (st) asm volatile("s_waitcnt vmcnt(6)" ::: "memory");
        else    asm volatile("s_waitcnt vmcnt(0)" ::: "memory");
      }
      asm volatile("s_barrier" ::: "memory");
    }
    ar = nar;
  }

  // ---- fused epilogue: v = acc/32 + b1; h' = relu(v)*lnw; LN stat partials ----
  float bi[4], lw[4];
#pragma unroll
  for (int n = 0; n < 4; ++n) {
    const long col = bcol + wc * 64 + n * 16 + fr;
    bi[n] = bias[col];
    lw[n] = lnw[col];
  }
  float* sred = (float*)smem;
  float* qred = sred + 1024;
  const long orow = brow + wr * 128 + fk * 4;
  const long ocol = bcol + wc * 64 + fr;
#pragma unroll
  for (int m = 0; m < 8; ++m) {
#pragma unroll
    for (int r = 0; r < 4; ++r) {
      const long row = orow + m * 16 + r;
      float s = 0.f, q = 0.f;
#pragma unroll
      for (int n = 0; n < 4; ++n) {
        float v = acc[m][n][r] * 0.03125f + bi[n];
        v = v > 0.f ? v : 0.f;
        s += v;
        q += v * v;
        C[row * (long)N + ocol + n * 16] = f2bf(v * lw[n]);
      }
#pragma unroll
      for (int off = 1; off < 16; off <<= 1) {
        s += __shfl_xor(s, off, 64);
        q += __shfl_xor(q, off, 64);
      }
      if (fr == 0) {
        int rl = wr * 128 + m * 16 + fk * 4 + r;
        sred[rl * 4 + wc] = s;
        qred[rl * 4 + wc] = q;
      }
    }
  }
  __syncthreads();
  if (t < 256) {
    float s = sred[t * 4] + sred[t * 4 + 1] + sred[t * 4 + 2] + sred[t * 4 + 3];
    float q = qred[t * 4] + qred[t * 4 + 1] + qred[t * 4 + 2] + qred[t * 4 + 3];
    float* pb = pp + (((long)(tm * 16 + tn) * 256 + t) * 2);
    pb[0] = s;
    pb[1] = q;
  }
#undef STAGE_A
#undef STAGE_B
#undef RD_A
#undef RD_B
#undef MFMA_QUAD
}

// ============ 256x128-tile bf16 GEMM2 (r13): out = (rs*G - rs*mu*w2l + b2l + b2)*gamma + x ============
__global__ __launch_bounds__(512, 2) void gemm256_g2(
    const unsigned short* __restrict__ A, const unsigned short* __restrict__ B,
    float* __restrict__ Cf, const float* __restrict__ bias,
    const float* __restrict__ gamma, const float* __restrict__ resid,
    const float* __restrict__ w2l, const float* __restrict__ b2l,
    const float* __restrict__ rowstats,
    int M, int N, int K) {
  extern __shared__ char smem[];
  const int NT = K >> 6;

  const int nwg = gridDim.x;
  const int cpx = nwg >> 3;
  const int bid = blockIdx.x;
  const int swz = (bid & 7) * cpx + (bid >> 3);
  const int tiles_m = M >> 8;
  const int tm = swz % tiles_m;
  const int tn = swz / tiles_m;
  const long brow = (long)tm * 256;
  const long bcol = (long)tn * 128;

  const int t = threadIdx.x;
  const int lane = t & 63, wv = t >> 6;
  const int wr = wv >> 1, wc = wv & 1;
  const int fr = lane & 15, fk = lane >> 4;

  const int srow = t >> 3;
  const int scol = 8 * ((t & 7) ^ ((t >> 3) & 7));
  const unsigned short* Asrc = A + (brow + srow) * (long)K + scol;
  const unsigned short* Bsrc = B + (bcol + srow) * (long)K + scol;
  const long hstep = (long)128 * K, lstep = (long)64 * K;

#define STAGE_A2(j, reg, h, L)                                                 \
  __builtin_amdgcn_global_load_lds(AS1(Asrc + (h)*hstep + (L)*lstep + (j)*64), \
      AS3(smem + (reg)*32768 + (h)*16384 + (L)*8192 + t * 16), 16, 0, 0)
#define STAGE_B2(j, L)                                                         \
  __builtin_amdgcn_global_load_lds(AS1(Bsrc + (L)*lstep + (j)*64),             \
      AS3(smem + 98304 + ((j)&1) * 16384 + (L)*8192 + t * 16), 16, 0, 0)

  const int xr = (fr & 7) << 4;
  const char* ArdRow = smem + (wr * 64 + fr) * 128;
  const char* BrdRow = smem + 98304 + (wc * 64 + fr) * 128;
#define RD_A2(ar_, m, kk) \
  (*(const s16x8*)(ArdRow + (ar_)*32768 + (m)*2048 + (((kk)*64 + fk * 16) ^ xr)))
#define RD_B2(pb_, n, kk) \
  (*(const s16x8*)(BrdRow + (pb_)*16384 + (n)*2048 + (((kk)*64 + fk * 16) ^ xr)))

  f32x4 acc[4][4];
#pragma unroll
  for (int m = 0; m < 4; m++)
#pragma unroll
    for (int n = 0; n < 4; n++) acc[m][n] = (f32x4)0.f;

  STAGE_A2(0, 0, 0, 0); STAGE_A2(0, 0, 0, 1); STAGE_A2(0, 0, 1, 0); STAGE_A2(0, 0, 1, 1);
  STAGE_B2(0, 0); STAGE_B2(0, 1);
  STAGE_A2(1, 1, 0, 0); STAGE_A2(1, 1, 0, 1); STAGE_A2(1, 1, 1, 0); STAGE_A2(1, 1, 1, 1);
  STAGE_B2(1, 0); STAGE_B2(1, 1);
  asm volatile("s_waitcnt vmcnt(6)" ::: "memory");
  __builtin_amdgcn_s_barrier();

  s16x8 bfr[4][2];
  s16x8 ap[2][2];
  ap[0][0] = RD_A2(0, 0, 0); ap[0][1] = RD_A2(0, 0, 1);

  int ar = 0;
  for (int g = 0; g < NT; ++g) {
    const int pb = g & 1;
    int sr = ar + 2; if (sr >= 3) sr -= 3;
    int nar = ar + 1; if (nar >= 3) nar = 0;
    const bool st = (g + 2 < NT);
#pragma unroll
    for (int p = 0; p < 4; ++p) {
      const int cs = p & 1, ns = cs ^ 1;
      if (p == 0) {
#pragma unroll
        for (int n = 0; n < 4; ++n) {
          bfr[n][0] = RD_B2(pb, n, 0);
          bfr[n][1] = RD_B2(pb, n, 1);
        }
      }
      asm volatile("s_waitcnt lgkmcnt(0)" ::: "memory");
      __builtin_amdgcn_sched_barrier(0);
      __builtin_amdgcn_s_setprio(1);
#pragma unroll
      for (int n = 0; n < 4; ++n) {
        acc[p][n] = __builtin_amdgcn_mfma_f32_16x16x32_bf16(
            ap[cs][0], bfr[n][0], acc[p][n], 0, 0, 0);
        acc[p][n] = __builtin_amdgcn_mfma_f32_16x16x32_bf16(
            ap[cs][1], bfr[n][1], acc[p][n], 0, 0, 0);
      }
      __builtin_amdgcn_s_setprio(0);
      if (p < 3) {
        ap[ns][0] = RD_A2(ar, p + 1, 0); ap[ns][1] = RD_A2(ar, p + 1, 1);
      } else if (g + 1 < NT) {
        ap[ns][0] = RD_A2(nar, 0, 0); ap[ns][1] = RD_A2(nar, 0, 1);
      }
      if (st) {
        if (p == 0) { STAGE_A2(g + 2, sr, 0, 0); STAGE_A2(g + 2, sr, 0, 1); }
        if (p == 1) { STAGE_A2(g + 2, sr, 1, 0); STAGE_A2(g + 2, sr, 1, 1); }
        if (p == 2) { STAGE_B2(g + 2, 0); STAGE_B2(g + 2, 1); }
      }
      if (p == 2 && g + 1 < NT) {
        if (st) asm volatile("s_waitcnt vmcnt(6)" ::: "memory");
        else    asm volatile("s_waitcnt vmcnt(0)" ::: "memory");
      }
      asm volatile("s_barrier" ::: "memory");
    }
    ar = nar;
  }

  float bi[4], ga[4], wl[4], bl[4];
#pragma unroll
  for (int n = 0; n < 4; ++n) {
    const long col = bcol + wc * 64 + n * 16 + fr;
    bi[n] = bias[col];
    ga[n] = gamma[col];
    wl[n] = w2l[col];
    bl[n] = b2l[col];
  }
  const long orow = brow + wr * 64 + fk * 4;
  const long ocol = bcol + wc * 64 + fr;
#pragma unroll
  for (int m = 0; m < 4; ++m)
#pragma unroll
    for (int r = 0; r < 4; ++r) {
      const long row = orow + m * 16 + r;
      const float mu = rowstats[row * 2];
      const float rs = rowstats[row * 2 + 1];
#pragma unroll
      for (int n = 0; n < 4; ++n) {
        const long col = ocol + n * 16;
        float v = rs * acc[m][n][r] - rs * mu * wl[n] + bl[n] + bi[n];
        Cf[row * (long)N + col] = v * ga[n] + resid[row * (long)N + col];
      }
    }
#undef STAGE_A2
#undef STAGE_B2
#undef RD_A2
#undef RD_B2
}

extern "C" void kernel_launch(void* const* d_in, const int* in_sizes, int n_in,
                              void* d_out, int out_size, void* d_ws, size_t ws_size,
                              hipStream_t stream) {
  const float* x     = (const float*)d_in[0];
  const float* W1    = (const float*)d_in[1];
  const float* b1    = (const float*)d_in[2];
  const float* ln_w  = (const float*)d_in[3];
  const float* ln_b  = (const float*)d_in[4];
  const float* W2    = (const float*)d_in[5];
  const float* b2    = (const float*)d_in[6];
  const float* gamma = (const float*)d_in[7];
  float* out = (float*)d_out;

  const int Nr = 8192, DIM = 1024, DFF = 4096, K1 = 3072;

  unsigned char* W1q    = (unsigned char*)d_ws;
  unsigned short* W2b   = (unsigned short*)(W1q + (long)DFF * K1);
  unsigned char* h_in   = (unsigned char*)(W2b + (long)DIM * DFF);
  unsigned short* h_act = (unsigned short*)(h_in + (long)Nr * K1);
  float* partial  = (float*)(h_act + (long)Nr * DFF);
  float* prefix   = partial + 128 * 1024;
  float* suffix   = prefix + 128 * 1024;
  float* pp       = suffix + 128 * 1024;
  float* rowstats = pp + 32 * 16 * 256 * 2;
  float* w2l      = rowstats + (long)Nr * 2;
  float* b2l      = w2l + DIM;

  hipFuncSetAttribute((const void*)gemm256_relu,
                      hipFuncAttributeMaxDynamicSharedMemorySize, 163840);
  hipFuncSetAttribute((const void*)gemm256_g2,
                      hipFuncAttributeMaxDynamicSharedMemorySize, 131072);

  cast_weights<<<2048, 256, 0, stream>>>(W1, W1q, (long)DFF * K1,
                                         W2, W2b, (long)DIM * DFF);

  scan_chunkmax<<<dim3(4, 128), 256, 0, stream>>>(x, partial);
  scan_chunkscan<<<4, 256, 0, stream>>>(partial, prefix, suffix);
  scan_emit<<<dim3(4, 128), 256, 0, stream>>>(x, prefix, suffix, h_in);

  w2_fold<<<DIM, 256, 0, stream>>>(W2, ln_w, ln_b, w2l, b2l);

  // GEMM1 (fp8, BK=128, global-pre-swizzled operands)
  gemm256_relu<<<512, 512, 163840, stream>>>(h_in, W1q, h_act, b1, ln_w, pp,
                                             Nr, DFF, K1);

  ln_stats_reduce<<<32, 256, 0, stream>>>(pp, rowstats);

  // GEMM2 (bf16): out = (rs*(h'@W2^T) - rs*mu*w2l + b2l + b2)*gamma + x
  gemm256_g2<<<256, 512, 131072, stream>>>(h_act, W2b, out, b2, gamma, x,
                                           w2l, b2l, rowstats, Nr, DIM, DFF);
}

// Round 16
// 297.169 us; speedup vs baseline: 2.0374x; 1.0601x over previous
//
#include <hip/hip_runtime.h>

typedef __attribute__((ext_vector_type(4))) float f32x4;
typedef __attribute__((ext_vector_type(8))) short s16x8;
typedef __attribute__((ext_vector_type(8))) unsigned short u16x8;

#define AS1(p) ((const __attribute__((address_space(1))) void*)(p))
#define AS3(p) ((__attribute__((address_space(3))) void*)(p))

__device__ __forceinline__ unsigned short f2bf(float f) {
  unsigned u = __builtin_bit_cast(unsigned, f);
  u += 0x7fffu + ((u >> 16) & 1u);
  return (unsigned short)(u >> 16);
}
__device__ __forceinline__ float bf2f(unsigned short s) {
  unsigned u = ((unsigned)s) << 16;
  return __builtin_bit_cast(float, u);
}
// fp32 -> OCP e4m3fn (RNE, FTZ below 2^-6, clamp 448)
__device__ __forceinline__ unsigned f2e4m3(float f) {
  unsigned uf = __builtin_bit_cast(unsigned, f);
  unsigned s = (uf >> 24) & 0x80u;
  unsigned u = uf & 0x7fffffffu;
  if (u < 0x3c800000u) return s;
  if (u > 0x43e00000u) u = 0x43e00000u;
  u += 0x7ffffu + ((u >> 20) & 1u);
  unsigned v = (u >> 20) - 960u;
  if (v > 126u) v = 126u;
  return s | v;
}

// r15/r16 global pre-swizzle rule for all fp8 GEMM operands (producers write it;
// GEMMs stage LINEARLY and read b64 with xr = fr<<3 — conflict-free, verified
// r15: 1.9e7 -> 98K):  phys_k = (k & ~127) | ((k & 127) ^ ((row & 15) << 3))

// ---------------- weight casts: W1, W2 -> fp8 (x32, pre-swizzled) ----------------
__global__ __launch_bounds__(256) void cast_weights(const float* __restrict__ W1,
                                                    unsigned char* __restrict__ W1q,
                                                    long n1,
                                                    const float* __restrict__ W2,
                                                    unsigned char* __restrict__ W2q,
                                                    long n2) {
  if (blockIdx.x < 1536) {
    long i = ((long)blockIdx.x * 256 + threadIdx.x) * 4;
    long stride = (long)1536 * 256 * 4;
    for (; i < n1; i += stride) {
      float4 f = *(const float4*)(W1 + i);
      unsigned v = f2e4m3(f.x * 32.f) | (f2e4m3(f.y * 32.f) << 8) |
                   (f2e4m3(f.z * 32.f) << 16) | (f2e4m3(f.w * 32.f) << 24);
      long n = i / 3072;
      long k = i - n * 3072;
      long phys = n * 3072 + (k & ~(long)127) + ((k & 127) ^ ((n & 15) << 3));
      *(unsigned*)(W1q + phys) = v;
    }
  } else {
    long i = ((long)(blockIdx.x - 1536) * 256 + threadIdx.x) * 4;
    long stride = (long)512 * 256 * 4;
    for (; i < n2; i += stride) {
      float4 f = *(const float4*)(W2 + i);
      unsigned v = f2e4m3(f.x * 32.f) | (f2e4m3(f.y * 32.f) << 8) |
                   (f2e4m3(f.z * 32.f) << 16) | (f2e4m3(f.w * 32.f) << 24);
      long n = i >> 12;
      long k = i & 4095;
      long phys = (n << 12) + (k & ~(long)127) + ((k & 127) ^ ((n & 15) << 3));
      *(unsigned*)(W2q + phys) = v;
    }
  }
}

// ---------------- LN fold: w2l = W2 @ lnw, b2l = W2 @ lnb ----------------
__global__ __launch_bounds__(256) void w2_fold(const float* __restrict__ W2,
                                               const float* __restrict__ lnw,
                                               const float* __restrict__ lnb,
                                               float* __restrict__ w2l,
                                               float* __restrict__ b2l) {
  const int n = blockIdx.x;
  const float* w = W2 + (long)n * 4096;
  float s = 0.f, b = 0.f;
  for (int k = threadIdx.x; k < 4096; k += 256) {
    float wv = w[k];
    s += wv * lnw[k];
    b += wv * lnb[k];
  }
#pragma unroll
  for (int off = 32; off; off >>= 1) {
    s += __shfl_xor(s, off, 64);
    b += __shfl_xor(b, off, 64);
  }
  __shared__ float ss[4], bb[4];
  const int wv2 = threadIdx.x >> 6;
  if ((threadIdx.x & 63) == 0) { ss[wv2] = s; bb[wv2] = b; }
  __syncthreads();
  if (threadIdx.x == 0) {
    w2l[n] = ss[0] + ss[1] + ss[2] + ss[3];
    b2l[n] = bb[0] + bb[1] + bb[2] + bb[3];
  }
}

// ---------------- hierarchical column cummax scan ----------------
__global__ __launch_bounds__(256) void scan_chunkmax(const float* __restrict__ x,
                                                     float* __restrict__ partial) {
  int col = blockIdx.x * 256 + threadIdx.x;
  int chunk = blockIdx.y;
  const float* p = x + (long)chunk * 64 * 1024 + col;
  float m = -INFINITY;
#pragma unroll 4
  for (int i = 0; i < 64; i++) m = fmaxf(m, p[(long)i * 1024]);
  partial[chunk * 1024 + col] = m;
}

__global__ __launch_bounds__(256) void scan_chunkscan(const float* __restrict__ partial,
                                                      float* __restrict__ prefix,
                                                      float* __restrict__ suffix) {
  int col = blockIdx.x * 256 + threadIdx.x;
  float v[128];
#pragma unroll
  for (int c = 0; c < 128; c++) v[c] = partial[c * 1024 + col];
  float run = -INFINITY;
#pragma unroll
  for (int c = 0; c < 128; c++) {
    prefix[c * 1024 + col] = run;
    run = fmaxf(run, v[c]);
  }
  run = -INFINITY;
#pragma unroll
  for (int c = 127; c >= 0; c--) {
    suffix[c * 1024 + col] = run;
    run = fmaxf(run, v[c]);
  }
}

// Emits h_in FP8 [8192, 3072] (x | before | after), pre-swizzled.
__global__ __launch_bounds__(256) void scan_emit(const float* __restrict__ x,
                                                 const float* __restrict__ prefix,
                                                 const float* __restrict__ suffix,
                                                 unsigned char* __restrict__ h_in) {
  int col = blockIdx.x * 256 + threadIdx.x;
  int chunk = blockIdx.y;
  long r0 = (long)chunk * 64;
  const int cb = col & ~127, cw = col & 127;
  float run = prefix[chunk * 1024 + col];
  for (int i = 0; i < 64; i++) {
    long row = r0 + i;
    int xo = (int)(row & 15) << 3;
    int c0 = cb | (cw ^ xo);
    float v = x[row * 1024 + col];
    unsigned char* hr = h_in + row * 3072;
    hr[c0] = (unsigned char)f2e4m3(v);
    hr[1024 + c0] = (unsigned char)(row == 0 ? 0u : f2e4m3(run));
    run = fmaxf(run, v);
  }
  float run2 = suffix[chunk * 1024 + col];
  for (int i = 63; i >= 0; i--) {
    long row = r0 + i;
    int xo = (int)(row & 15) << 3;
    int c0 = cb | (cw ^ xo);
    float v = x[row * 1024 + col];
    h_in[row * 3072 + 2048 + c0] = (unsigned char)(row == 8191 ? 0u : f2e4m3(run2));
    run2 = fmaxf(run2, v);
  }
}

// ---------------- rowstats reducer ----------------
__global__ __launch_bounds__(256) void ln_stats_reduce(const float* __restrict__ pp,
                                                       float* __restrict__ rowstats) {
  int row = blockIdx.x * 256 + threadIdx.x;
  int tm = row >> 8, rl = row & 255;
  float s = 0.f, q = 0.f;
#pragma unroll
  for (int tn = 0; tn < 16; ++tn) {
    const float* p = pp + (((long)(tm * 16 + tn) * 256 + rl) * 2);
    s += p[0];
    q += p[1];
  }
  float mu = s * (1.f / 4096.f);
  float var = q * (1.f / 4096.f) - mu * mu;
  rowstats[row * 2] = mu;
  rowstats[row * 2 + 1] = rsqrtf(var + 1e-6f);
}

// ============ 256x256 FP8 GEMM1, BK=128 (r15 verified): h' fp8 out (r16) ============
__global__ __launch_bounds__(512, 2) void gemm256_relu(
    const unsigned char* __restrict__ A, const unsigned char* __restrict__ B,
    unsigned char* __restrict__ C, const float* __restrict__ bias,
    const float* __restrict__ lnw, float* __restrict__ pp,
    int M, int N, int K) {
  extern __shared__ char smem[];
  const int NT = K >> 7;

  const int nwg = gridDim.x;
  const int cpx = nwg >> 3;
  const int bid = blockIdx.x;
  const int swz = (bid & 7) * cpx + (bid >> 3);
  const int tiles_m = M >> 8;
  const int tm = swz % tiles_m;
  const int tn = swz / tiles_m;
  const long brow = (long)tm * 256;
  const long bcol = (long)tn * 256;

  const int t = threadIdx.x;
  const int lane = t & 63, wv = t >> 6;
  const int wr = wv >> 2, wc = wv & 3;
  const int fr = lane & 15, fk = lane >> 4;

  const int srow = t >> 3;
  const int scol = (t & 7) * 16;
  const unsigned char* Asrc = A + (brow + srow) * (long)K + scol;
  const unsigned char* Bsrc = B + (bcol + srow) * (long)K + scol;
  const long hstep = (long)128 * K, lstep = (long)64 * K;

#define STAGE_A(j, reg, h, L)                                                   \
  __builtin_amdgcn_global_load_lds(AS1(Asrc + (h)*hstep + (L)*lstep + (j)*128), \
      AS3(smem + (reg)*32768 + (h)*16384 + (L)*8192 + t * 16), 16, 0, 0)
#define STAGE_B(j, h, L)                                                        \
  __builtin_amdgcn_global_load_lds(AS1(Bsrc + (h)*hstep + (L)*lstep + (j)*128), \
      AS3(smem + 98304 + ((j)&1) * 32768 + (h)*16384 + (L)*8192 + t * 16), 16, 0, 0)

  const int xr = fr << 3;
  const char* ArdRow = smem + (wr * 128 + fr) * 128;
  const char* BrdRow = smem + 98304 + (wc * 64 + fr) * 128;
#define RD_A(ar_, m, kk) \
  (*(const long*)(ArdRow + (ar_)*32768 + (m)*2048 + (((kk)*32 + fk * 8) ^ xr)))
#define RD_B(pb_, n, kk) \
  (*(const long*)(BrdRow + (pb_)*32768 + (n)*2048 + (((kk)*32 + fk * 8) ^ xr)))

#define MFMA_QUAD(mi, a_)                                                      \
  _Pragma("unroll")                                                            \
  for (int n = 0; n < 4; ++n) {                                                \
    _Pragma("unroll")                                                          \
    for (int kk = 0; kk < 4; ++kk)                                             \
      acc[(mi)][n] = __builtin_amdgcn_mfma_f32_16x16x32_fp8_fp8(               \
          a_[kk], bfr[n][kk], acc[(mi)][n], 0, 0, 0);                          \
  }

  f32x4 acc[8][4];
#pragma unroll
  for (int m = 0; m < 8; m++)
#pragma unroll
    for (int n = 0; n < 4; n++) acc[m][n] = (f32x4)0.f;

  STAGE_A(0, 0, 0, 0); STAGE_A(0, 0, 0, 1); STAGE_A(0, 0, 1, 0); STAGE_A(0, 0, 1, 1);
  STAGE_B(0, 0, 0); STAGE_B(0, 0, 1); STAGE_B(0, 1, 0); STAGE_B(0, 1, 1);
  STAGE_A(1, 1, 0, 0); STAGE_A(1, 1, 0, 1); STAGE_A(1, 1, 1, 0); STAGE_A(1, 1, 1, 1);
  STAGE_B(1, 0, 0); STAGE_B(1, 0, 1); STAGE_B(1, 1, 0); STAGE_B(1, 1, 1);
  asm volatile("s_waitcnt vmcnt(8)" ::: "memory");
  __builtin_amdgcn_s_barrier();

  long bfr[4][4];
  long ap[2][2][4];
  ap[0][0][0] = RD_A(0, 0, 0); ap[0][0][1] = RD_A(0, 0, 1);
  ap[0][0][2] = RD_A(0, 0, 2); ap[0][0][3] = RD_A(0, 0, 3);
  ap[0][1][0] = RD_A(0, 1, 0); ap[0][1][1] = RD_A(0, 1, 1);
  ap[0][1][2] = RD_A(0, 1, 2); ap[0][1][3] = RD_A(0, 1, 3);

  int ar = 0;
  for (int g = 0; g < NT; ++g) {
    const int pb = g & 1;
    int sr = ar + 2; if (sr >= 3) sr -= 3;
    int nar = ar + 1; if (nar >= 3) nar = 0;
    const bool st = (g + 2 < NT);
#pragma unroll
    for (int p = 0; p < 4; ++p) {
      const int cs = p & 1, ns = cs ^ 1;
      if (p == 0) {
#pragma unroll
        for (int n = 0; n < 4; ++n)
#pragma unroll
          for (int kk = 0; kk < 4; ++kk) bfr[n][kk] = RD_B(pb, n, kk);
      }
      asm volatile("s_waitcnt lgkmcnt(0)" ::: "memory");
      __builtin_amdgcn_sched_barrier(0);
      __builtin_amdgcn_s_setprio(1);
      MFMA_QUAD(2 * p, ap[cs][0])
      MFMA_QUAD(2 * p + 1, ap[cs][1])
      __builtin_amdgcn_s_setprio(0);
      if (p < 3) {
#pragma unroll
        for (int kk = 0; kk < 4; ++kk) {
          ap[ns][0][kk] = RD_A(ar, 2 * p + 2, kk);
          ap[ns][1][kk] = RD_A(ar, 2 * p + 3, kk);
        }
      } else if (g + 1 < NT) {
#pragma unroll
        for (int kk = 0; kk < 4; ++kk) {
          ap[ns][0][kk] = RD_A(nar, 0, kk);
          ap[ns][1][kk] = RD_A(nar, 1, kk);
        }
      }
      if (st) {
        if (p == 0) { STAGE_A(g + 2, sr, 0, 0); STAGE_A(g + 2, sr, 0, 1); }
        if (p == 1) { STAGE_A(g + 2, sr, 1, 0); STAGE_A(g + 2, sr, 1, 1); }
        if (p == 2) { STAGE_B(g + 2, 0, 0); STAGE_B(g + 2, 0, 1); }
        if (p == 3) { STAGE_B(g + 2, 1, 0); STAGE_B(g + 2, 1, 1); }
      }
      if (p == 2 && g + 1 < NT) {
        if (st) asm volatile("s_waitcnt vmcnt(6)" ::: "memory");
        else    asm volatile("s_waitcnt vmcnt(0)" ::: "memory");
      }
      asm volatile("s_barrier" ::: "memory");
    }
    ar = nar;
  }

  // ---- epilogue: v = acc/32 + b1; h' = relu(v)*lnw -> FP8 pre-swizzled; LN stats ----
  float bi[4], lw[4];
#pragma unroll
  for (int n = 0; n < 4; ++n) {
    const long col = bcol + wc * 64 + n * 16 + fr;
    bi[n] = bias[col];
    lw[n] = lnw[col];
  }
  float* sred = (float*)smem;
  float* qred = sred + 1024;
  const long orow = brow + wr * 128 + fk * 4;
  const int ocol = (int)bcol + wc * 64 + fr;
#pragma unroll
  for (int m = 0; m < 8; ++m) {
#pragma unroll
    for (int r = 0; r < 4; ++r) {
      const long row = orow + m * 16 + r;
      const int xo = ((fk * 4 + r) & 15) << 3;  // row & 15
      float s = 0.f, q = 0.f;
#pragma unroll
      for (int n = 0; n < 4; ++n) {
        float v = acc[m][n][r] * 0.03125f + bi[n];
        v = v > 0.f ? v : 0.f;
        s += v;
        q += v * v;
        const int col = ocol + n * 16;
        const int phys = (col & ~127) | ((col & 127) ^ xo);
        C[row * (long)N + phys] = (unsigned char)f2e4m3(v * lw[n]);
      }
#pragma unroll
      for (int off = 1; off < 16; off <<= 1) {
        s += __shfl_xor(s, off, 64);
        q += __shfl_xor(q, off, 64);
      }
      if (fr == 0) {
        int rl = wr * 128 + m * 16 + fk * 4 + r;
        sred[rl * 4 + wc] = s;
        qred[rl * 4 + wc] = q;
      }
    }
  }
  __syncthreads();
  if (t < 256) {
    float s = sred[t * 4] + sred[t * 4 + 1] + sred[t * 4 + 2] + sred[t * 4 + 3];
    float q = qred[t * 4] + qred[t * 4 + 1] + qred[t * 4 + 2] + qred[t * 4 + 3];
    float* pb = pp + (((long)(tm * 16 + tn) * 256 + t) * 2);
    pb[0] = s;
    pb[1] = q;
  }
#undef STAGE_A
#undef STAGE_B
#undef RD_A
#undef RD_B
#undef MFMA_QUAD
}

// ============ 256x128 FP8 GEMM2, BK=128 (r16): out = (rs*G/32 - rs*mu*w2l + b2l + b2)*gamma + x ============
// Same recipe as GEMM1: pre-swizzled global operands, linear staging, xr=fr<<3.
// 8 waves 4Mx2N, per-wave 64x64. LDS: A 3x32K @0/32/64K, B 2x16K @96/112K = 128KB.
// 6 loads/tile (p0/p1: A, p2: B); vmcnt(6) at p2; NT = 4096/128 = 32.
__global__ __launch_bounds__(512, 2) void gemm256_g2(
    const unsigned char* __restrict__ A, const unsigned char* __restrict__ B,
    float* __restrict__ Cf, const float* __restrict__ bias,
    const float* __restrict__ gamma, const float* __restrict__ resid,
    const float* __restrict__ w2l, const float* __restrict__ b2l,
    const float* __restrict__ rowstats,
    int M, int N, int K) {
  extern __shared__ char smem[];
  const int NT = K >> 7;

  const int nwg = gridDim.x;
  const int cpx = nwg >> 3;
  const int bid = blockIdx.x;
  const int swz = (bid & 7) * cpx + (bid >> 3);
  const int tiles_m = M >> 8;
  const int tm = swz % tiles_m;
  const int tn = swz / tiles_m;
  const long brow = (long)tm * 256;
  const long bcol = (long)tn * 128;

  const int t = threadIdx.x;
  const int lane = t & 63, wv = t >> 6;
  const int wr = wv >> 1, wc = wv & 1;
  const int fr = lane & 15, fk = lane >> 4;

  const int srow = t >> 3;
  const int scol = (t & 7) * 16;
  const unsigned char* Asrc = A + (brow + srow) * (long)K + scol;
  const unsigned char* Bsrc = B + (bcol + srow) * (long)K + scol;
  const long hstep = (long)128 * K, lstep = (long)64 * K;

#define STAGE_A2(j, reg, h, L)                                                  \
  __builtin_amdgcn_global_load_lds(AS1(Asrc + (h)*hstep + (L)*lstep + (j)*128), \
      AS3(smem + (reg)*32768 + (h)*16384 + (L)*8192 + t * 16), 16, 0, 0)
#define STAGE_B2(j, L)                                                          \
  __builtin_amdgcn_global_load_lds(AS1(Bsrc + (L)*lstep + (j)*128),             \
      AS3(smem + 98304 + ((j)&1) * 16384 + (L)*8192 + t * 16), 16, 0, 0)

  const int xr = fr << 3;
  const char* ArdRow = smem + (wr * 64 + fr) * 128;
  const char* BrdRow = smem + 98304 + (wc * 64 + fr) * 128;
#define RD_A2(ar_, m, kk) \
  (*(const long*)(ArdRow + (ar_)*32768 + (m)*2048 + (((kk)*32 + fk * 8) ^ xr)))
#define RD_B2(pb_, n, kk) \
  (*(const long*)(BrdRow + (pb_)*16384 + (n)*2048 + (((kk)*32 + fk * 8) ^ xr)))

  f32x4 acc[4][4];
#pragma unroll
  for (int m = 0; m < 4; m++)
#pragma unroll
    for (int n = 0; n < 4; n++) acc[m][n] = (f32x4)0.f;

  // prologue: A0(4), B0(2), A1(4), B1(2) = 12 loads; vmcnt(6) lands tile0
  STAGE_A2(0, 0, 0, 0); STAGE_A2(0, 0, 0, 1); STAGE_A2(0, 0, 1, 0); STAGE_A2(0, 0, 1, 1);
  STAGE_B2(0, 0); STAGE_B2(0, 1);
  STAGE_A2(1, 1, 0, 0); STAGE_A2(1, 1, 0, 1); STAGE_A2(1, 1, 1, 0); STAGE_A2(1, 1, 1, 1);
  STAGE_B2(1, 0); STAGE_B2(1, 1);
  asm volatile("s_waitcnt vmcnt(6)" ::: "memory");
  __builtin_amdgcn_s_barrier();

  long bfr[4][4];
  long ap[2][4];
  ap[0][0] = RD_A2(0, 0, 0); ap[0][1] = RD_A2(0, 0, 1);
  ap[0][2] = RD_A2(0, 0, 2); ap[0][3] = RD_A2(0, 0, 3);

  int ar = 0;
  for (int g = 0; g < NT; ++g) {
    const int pb = g & 1;
    int sr = ar + 2; if (sr >= 3) sr -= 3;
    int nar = ar + 1; if (nar >= 3) nar = 0;
    const bool st = (g + 2 < NT);
#pragma unroll
    for (int p = 0; p < 4; ++p) {
      const int cs = p & 1, ns = cs ^ 1;
      if (p == 0) {
#pragma unroll
        for (int n = 0; n < 4; ++n)
#pragma unroll
          for (int kk = 0; kk < 4; ++kk) bfr[n][kk] = RD_B2(pb, n, kk);
      }
      asm volatile("s_waitcnt lgkmcnt(0)" ::: "memory");
      __builtin_amdgcn_sched_barrier(0);
      __builtin_amdgcn_s_setprio(1);
#pragma unroll
      for (int n = 0; n < 4; ++n)
#pragma unroll
        for (int kk = 0; kk < 4; ++kk)
          acc[p][n] = __builtin_amdgcn_mfma_f32_16x16x32_fp8_fp8(
              ap[cs][kk], bfr[n][kk], acc[p][n], 0, 0, 0);
      __builtin_amdgcn_s_setprio(0);
      if (p < 3) {
#pragma unroll
        for (int kk = 0; kk < 4; ++kk) ap[ns][kk] = RD_A2(ar, p + 1, kk);
      } else if (g + 1 < NT) {
#pragma unroll
        for (int kk = 0; kk < 4; ++kk) ap[ns][kk] = RD_A2(nar, 0, kk);
      }
      if (st) {
        if (p == 0) { STAGE_A2(g + 2, sr, 0, 0); STAGE_A2(g + 2, sr, 0, 1); }
        if (p == 1) { STAGE_A2(g + 2, sr, 1, 0); STAGE_A2(g + 2, sr, 1, 1); }
        if (p == 2) { STAGE_B2(g + 2, 0); STAGE_B2(g + 2, 1); }
      }
      if (p == 2 && g + 1 < NT) {
        if (st) asm volatile("s_waitcnt vmcnt(6)" ::: "memory");
        else    asm volatile("s_waitcnt vmcnt(0)" ::: "memory");
      }
      asm volatile("s_barrier" ::: "memory");
    }
    ar = nar;
  }

  float bi[4], ga[4], wl[4], bl[4];
#pragma unroll
  for (int n = 0; n < 4; ++n) {
    const long col = bcol + wc * 64 + n * 16 + fr;
    bi[n] = bias[col];
    ga[n] = gamma[col];
    wl[n] = w2l[col];
    bl[n] = b2l[col];
  }
  const long orow = brow + wr * 64 + fk * 4;
  const long ocol = bcol + wc * 64 + fr;
#pragma unroll
  for (int m = 0; m < 4; ++m)
#pragma unroll
    for (int r = 0; r < 4; ++r) {
      const long row = orow + m * 16 + r;
      const float mu = rowstats[row * 2];
      const float rs = rowstats[row * 2 + 1];
#pragma unroll
      for (int n = 0; n < 4; ++n) {
        const long col = ocol + n * 16;
        float v = rs * (acc[m][n][r] * 0.03125f) - rs * mu * wl[n] + bl[n] + bi[n];
        Cf[row * (long)N + col] = v * ga[n] + resid[row * (long)N + col];
      }
    }
#undef STAGE_A2
#undef STAGE_B2
#undef RD_A2
#undef RD_B2
}

extern "C" void kernel_launch(void* const* d_in, const int* in_sizes, int n_in,
                              void* d_out, int out_size, void* d_ws, size_t ws_size,
                              hipStream_t stream) {
  const float* x     = (const float*)d_in[0];
  const float* W1    = (const float*)d_in[1];
  const float* b1    = (const float*)d_in[2];
  const float* ln_w  = (const float*)d_in[3];
  const float* ln_b  = (const float*)d_in[4];
  const float* W2    = (const float*)d_in[5];
  const float* b2    = (const float*)d_in[6];
  const float* gamma = (const float*)d_in[7];
  float* out = (float*)d_out;

  const int Nr = 8192, DIM = 1024, DFF = 4096, K1 = 3072;

  unsigned char* W1q   = (unsigned char*)d_ws;                       // 12.58 MB
  unsigned char* W2q   = W1q + (long)DFF * K1;                       // 4.19 MB
  unsigned char* h_in  = W2q + (long)DIM * DFF;                      // 25.2 MB
  unsigned char* h_act = h_in + (long)Nr * K1;                       // 33.5 MB fp8
  float* partial  = (float*)(h_act + (long)Nr * DFF);
  float* prefix   = partial + 128 * 1024;
  float* suffix   = prefix + 128 * 1024;
  float* pp       = suffix + 128 * 1024;
  float* rowstats = pp + 32 * 16 * 256 * 2;
  float* w2l      = rowstats + (long)Nr * 2;
  float* b2l      = w2l + DIM;

  hipFuncSetAttribute((const void*)gemm256_relu,
                      hipFuncAttributeMaxDynamicSharedMemorySize, 163840);
  hipFuncSetAttribute((const void*)gemm256_g2,
                      hipFuncAttributeMaxDynamicSharedMemorySize, 131072);

  cast_weights<<<2048, 256, 0, stream>>>(W1, W1q, (long)DFF * K1,
                                         W2, W2q, (long)DIM * DFF);

  scan_chunkmax<<<dim3(4, 128), 256, 0, stream>>>(x, partial);
  scan_chunkscan<<<4, 256, 0, stream>>>(partial, prefix, suffix);
  scan_emit<<<dim3(4, 128), 256, 0, stream>>>(x, prefix, suffix, h_in);

  w2_fold<<<DIM, 256, 0, stream>>>(W2, ln_w, ln_b, w2l, b2l);

  // GEMM1 (fp8 BK=128): h' = relu(h_in @ W1q^T / 32 + b1)*lnw -> fp8, + LN stats
  gemm256_relu<<<512, 512, 163840, stream>>>(h_in, W1q, h_act, b1, ln_w, pp,
                                             Nr, DFF, K1);

  ln_stats_reduce<<<32, 256, 0, stream>>>(pp, rowstats);

  // GEMM2 (fp8 BK=128): out = (rs*(h'@W2q^T)/32 - rs*mu*w2l + b2l + b2)*gamma + x
  gemm256_g2<<<256, 512, 131072, stream>>>(h_act, W2q, out, b2, gamma, x,
                                           w2l, b2l, rowstats, Nr, DIM, DFF);
}

// Round 17
// 282.615 us; speedup vs baseline: 2.1424x; 1.0515x over previous
//
#include <hip/hip_runtime.h>

typedef __attribute__((ext_vector_type(4))) float f32x4;

#define AS1(p) ((const __attribute__((address_space(1))) void*)(p))
#define AS3(p) ((__attribute__((address_space(3))) void*)(p))

__device__ __forceinline__ unsigned short f2bf(float f) {
  unsigned u = __builtin_bit_cast(unsigned, f);
  u += 0x7fffu + ((u >> 16) & 1u);
  return (unsigned short)(u >> 16);
}
// fp32 -> OCP e4m3fn (RNE, FTZ below 2^-6, clamp 448)
__device__ __forceinline__ unsigned f2e4m3(float f) {
  unsigned uf = __builtin_bit_cast(unsigned, f);
  unsigned s = (uf >> 24) & 0x80u;
  unsigned u = uf & 0x7fffffffu;
  if (u < 0x3c800000u) return s;
  if (u > 0x43e00000u) u = 0x43e00000u;
  u += 0x7ffffu + ((u >> 20) & 1u);
  unsigned v = (u >> 20) - 960u;
  if (v > 126u) v = 126u;
  return s | v;
}

// Global pre-swizzle rule for fp8 GEMM operands (verified r15: conflicts 1.9e7->98K):
//   phys_k = (k & ~127) | ((k & 127) ^ ((row & 15) << 3))

// ---------------- r17 fused prep: W1/W2 fp8 casts + chunkmax + w2_fold ----------------
__global__ __launch_bounds__(256) void prep(const float* __restrict__ W1,
                                            unsigned char* __restrict__ W1q,
                                            const float* __restrict__ W2,
                                            unsigned char* __restrict__ W2q,
                                            const float* __restrict__ x,
                                            float* __restrict__ partial,
                                            const float* __restrict__ lnw,
                                            const float* __restrict__ lnb,
                                            float* __restrict__ w2l,
                                            float* __restrict__ b2l) {
  __shared__ float ss[4], bb[4];
  const int bid = blockIdx.x;
  if (bid < 1536) {
    // W1 -> fp8 x32, pre-swizzled. n1 = 4096*3072
    long i = ((long)bid * 256 + threadIdx.x) * 4;
    const long n1 = (long)4096 * 3072;
    const long stride = (long)1536 * 256 * 4;
    for (; i < n1; i += stride) {
      float4 f = *(const float4*)(W1 + i);
      unsigned v = f2e4m3(f.x * 32.f) | (f2e4m3(f.y * 32.f) << 8) |
                   (f2e4m3(f.z * 32.f) << 16) | (f2e4m3(f.w * 32.f) << 24);
      long n = i / 3072;
      long k = i - n * 3072;
      long phys = n * 3072 + (k & ~(long)127) + ((k & 127) ^ ((n & 15) << 3));
      *(unsigned*)(W1q + phys) = v;
    }
  } else if (bid < 2048) {
    // W2 -> fp8 x32, pre-swizzled. n2 = 1024*4096
    long i = ((long)(bid - 1536) * 256 + threadIdx.x) * 4;
    const long n2 = (long)1024 * 4096;
    const long stride = (long)512 * 256 * 4;
    for (; i < n2; i += stride) {
      float4 f = *(const float4*)(W2 + i);
      unsigned v = f2e4m3(f.x * 32.f) | (f2e4m3(f.y * 32.f) << 8) |
                   (f2e4m3(f.z * 32.f) << 16) | (f2e4m3(f.w * 32.f) << 24);
      long n = i >> 12;
      long k = i & 4095;
      long phys = (n << 12) + (k & ~(long)127) + ((k & 127) ^ ((n & 15) << 3));
      *(unsigned*)(W2q + phys) = v;
    }
  } else if (bid < 2560) {
    // chunkmax: b = 0..511 -> colblk = b&3, chunk = b>>2
    const int b = bid - 2048;
    const int col = (b & 3) * 256 + threadIdx.x;
    const int chunk = b >> 2;
    const float* p = x + (long)chunk * 64 * 1024 + col;
    float m = -INFINITY;
#pragma unroll 4
    for (int i = 0; i < 64; i++) m = fmaxf(m, p[(long)i * 1024]);
    partial[chunk * 1024 + col] = m;
  } else {
    // w2_fold: n = 0..1023
    const int n = bid - 2560;
    const float* w = W2 + (long)n * 4096;
    float s = 0.f, b = 0.f;
    for (int k = threadIdx.x; k < 4096; k += 256) {
      float wv = w[k];
      s += wv * lnw[k];
      b += wv * lnb[k];
    }
#pragma unroll
    for (int off = 32; off; off >>= 1) {
      s += __shfl_xor(s, off, 64);
      b += __shfl_xor(b, off, 64);
    }
    const int wv2 = threadIdx.x >> 6;
    if ((threadIdx.x & 63) == 0) { ss[wv2] = s; bb[wv2] = b; }
    __syncthreads();
    if (threadIdx.x == 0) {
      w2l[n] = ss[0] + ss[1] + ss[2] + ss[3];
      b2l[n] = bb[0] + bb[1] + bb[2] + bb[3];
    }
  }
}

// ---------------- scan_emit with inline chunk-scan (r17): h_in fp8 pre-swizzled ----------------
__global__ __launch_bounds__(256) void scan_emit(const float* __restrict__ x,
                                                 const float* __restrict__ partial,
                                                 unsigned char* __restrict__ h_in) {
  const int col = blockIdx.x * 256 + threadIdx.x;
  const int chunk = blockIdx.y;
  // inline exclusive chunk prefix/suffix max over the 128 chunk partials
  float pre = -INFINITY, suf = -INFINITY;
#pragma unroll
  for (int c = 0; c < 128; ++c) {
    float pv = partial[c * 1024 + col];
    if (c < chunk) pre = fmaxf(pre, pv);
    if (c > chunk) suf = fmaxf(suf, pv);
  }
  long r0 = (long)chunk * 64;
  const int cb = col & ~127, cw = col & 127;
  float run = pre;
  for (int i = 0; i < 64; i++) {
    long row = r0 + i;
    int xo = (int)(row & 15) << 3;
    int c0 = cb | (cw ^ xo);
    float v = x[row * 1024 + col];
    unsigned char* hr = h_in + row * 3072;
    hr[c0] = (unsigned char)f2e4m3(v);
    hr[1024 + c0] = (unsigned char)(row == 0 ? 0u : f2e4m3(run));
    run = fmaxf(run, v);
  }
  float run2 = suf;
  for (int i = 63; i >= 0; i--) {
    long row = r0 + i;
    int xo = (int)(row & 15) << 3;
    int c0 = cb | (cw ^ xo);
    float v = x[row * 1024 + col];
    h_in[row * 3072 + 2048 + c0] = (unsigned char)(row == 8191 ? 0u : f2e4m3(run2));
    run2 = fmaxf(run2, v);
  }
}

// ============ 256x256 FP8 GEMM1, BK=128 (r15/r16 verified, unchanged) ============
__global__ __launch_bounds__(512, 2) void gemm256_relu(
    const unsigned char* __restrict__ A, const unsigned char* __restrict__ B,
    unsigned char* __restrict__ C, const float* __restrict__ bias,
    const float* __restrict__ lnw, float* __restrict__ pp,
    int M, int N, int K) {
  extern __shared__ char smem[];
  const int NT = K >> 7;

  const int nwg = gridDim.x;
  const int cpx = nwg >> 3;
  const int bid = blockIdx.x;
  const int swz = (bid & 7) * cpx + (bid >> 3);
  const int tiles_m = M >> 8;
  const int tm = swz % tiles_m;
  const int tn = swz / tiles_m;
  const long brow = (long)tm * 256;
  const long bcol = (long)tn * 256;

  const int t = threadIdx.x;
  const int lane = t & 63, wv = t >> 6;
  const int wr = wv >> 2, wc = wv & 3;
  const int fr = lane & 15, fk = lane >> 4;

  const int srow = t >> 3;
  const int scol = (t & 7) * 16;
  const unsigned char* Asrc = A + (brow + srow) * (long)K + scol;
  const unsigned char* Bsrc = B + (bcol + srow) * (long)K + scol;
  const long hstep = (long)128 * K, lstep = (long)64 * K;

#define STAGE_A(j, reg, h, L)                                                   \
  __builtin_amdgcn_global_load_lds(AS1(Asrc + (h)*hstep + (L)*lstep + (j)*128), \
      AS3(smem + (reg)*32768 + (h)*16384 + (L)*8192 + t * 16), 16, 0, 0)
#define STAGE_B(j, h, L)                                                        \
  __builtin_amdgcn_global_load_lds(AS1(Bsrc + (h)*hstep + (L)*lstep + (j)*128), \
      AS3(smem + 98304 + ((j)&1) * 32768 + (h)*16384 + (L)*8192 + t * 16), 16, 0, 0)

  const int xr = fr << 3;
  const char* ArdRow = smem + (wr * 128 + fr) * 128;
  const char* BrdRow = smem + 98304 + (wc * 64 + fr) * 128;
#define RD_A(ar_, m, kk) \
  (*(const long*)(ArdRow + (ar_)*32768 + (m)*2048 + (((kk)*32 + fk * 8) ^ xr)))
#define RD_B(pb_, n, kk) \
  (*(const long*)(BrdRow + (pb_)*32768 + (n)*2048 + (((kk)*32 + fk * 8) ^ xr)))

#define MFMA_QUAD(mi, a_)                                                      \
  _Pragma("unroll")                                                            \
  for (int n = 0; n < 4; ++n) {                                                \
    _Pragma("unroll")                                                          \
    for (int kk = 0; kk < 4; ++kk)                                             \
      acc[(mi)][n] = __builtin_amdgcn_mfma_f32_16x16x32_fp8_fp8(               \
          a_[kk], bfr[n][kk], acc[(mi)][n], 0, 0, 0);                          \
  }

  f32x4 acc[8][4];
#pragma unroll
  for (int m = 0; m < 8; m++)
#pragma unroll
    for (int n = 0; n < 4; n++) acc[m][n] = (f32x4)0.f;

  STAGE_A(0, 0, 0, 0); STAGE_A(0, 0, 0, 1); STAGE_A(0, 0, 1, 0); STAGE_A(0, 0, 1, 1);
  STAGE_B(0, 0, 0); STAGE_B(0, 0, 1); STAGE_B(0, 1, 0); STAGE_B(0, 1, 1);
  STAGE_A(1, 1, 0, 0); STAGE_A(1, 1, 0, 1); STAGE_A(1, 1, 1, 0); STAGE_A(1, 1, 1, 1);
  STAGE_B(1, 0, 0); STAGE_B(1, 0, 1); STAGE_B(1, 1, 0); STAGE_B(1, 1, 1);
  asm volatile("s_waitcnt vmcnt(8)" ::: "memory");
  __builtin_amdgcn_s_barrier();

  long bfr[4][4];
  long ap[2][2][4];
  ap[0][0][0] = RD_A(0, 0, 0); ap[0][0][1] = RD_A(0, 0, 1);
  ap[0][0][2] = RD_A(0, 0, 2); ap[0][0][3] = RD_A(0, 0, 3);
  ap[0][1][0] = RD_A(0, 1, 0); ap[0][1][1] = RD_A(0, 1, 1);
  ap[0][1][2] = RD_A(0, 1, 2); ap[0][1][3] = RD_A(0, 1, 3);

  int ar = 0;
  for (int g = 0; g < NT; ++g) {
    const int pb = g & 1;
    int sr = ar + 2; if (sr >= 3) sr -= 3;
    int nar = ar + 1; if (nar >= 3) nar = 0;
    const bool st = (g + 2 < NT);
#pragma unroll
    for (int p = 0; p < 4; ++p) {
      const int cs = p & 1, ns = cs ^ 1;
      if (p == 0) {
#pragma unroll
        for (int n = 0; n < 4; ++n)
#pragma unroll
          for (int kk = 0; kk < 4; ++kk) bfr[n][kk] = RD_B(pb, n, kk);
      }
      asm volatile("s_waitcnt lgkmcnt(0)" ::: "memory");
      __builtin_amdgcn_sched_barrier(0);
      __builtin_amdgcn_s_setprio(1);
      MFMA_QUAD(2 * p, ap[cs][0])
      MFMA_QUAD(2 * p + 1, ap[cs][1])
      __builtin_amdgcn_s_setprio(0);
      if (p < 3) {
#pragma unroll
        for (int kk = 0; kk < 4; ++kk) {
          ap[ns][0][kk] = RD_A(ar, 2 * p + 2, kk);
          ap[ns][1][kk] = RD_A(ar, 2 * p + 3, kk);
        }
      } else if (g + 1 < NT) {
#pragma unroll
        for (int kk = 0; kk < 4; ++kk) {
          ap[ns][0][kk] = RD_A(nar, 0, kk);
          ap[ns][1][kk] = RD_A(nar, 1, kk);
        }
      }
      if (st) {
        if (p == 0) { STAGE_A(g + 2, sr, 0, 0); STAGE_A(g + 2, sr, 0, 1); }
        if (p == 1) { STAGE_A(g + 2, sr, 1, 0); STAGE_A(g + 2, sr, 1, 1); }
        if (p == 2) { STAGE_B(g + 2, 0, 0); STAGE_B(g + 2, 0, 1); }
        if (p == 3) { STAGE_B(g + 2, 1, 0); STAGE_B(g + 2, 1, 1); }
      }
      if (p == 2 && g + 1 < NT) {
        if (st) asm volatile("s_waitcnt vmcnt(6)" ::: "memory");
        else    asm volatile("s_waitcnt vmcnt(0)" ::: "memory");
      }
      asm volatile("s_barrier" ::: "memory");
    }
    ar = nar;
  }

  float bi[4], lw[4];
#pragma unroll
  for (int n = 0; n < 4; ++n) {
    const long col = bcol + wc * 64 + n * 16 + fr;
    bi[n] = bias[col];
    lw[n] = lnw[col];
  }
  float* sred = (float*)smem;
  float* qred = sred + 1024;
  const long orow = brow + wr * 128 + fk * 4;
  const int ocol = (int)bcol + wc * 64 + fr;
#pragma unroll
  for (int m = 0; m < 8; ++m) {
#pragma unroll
    for (int r = 0; r < 4; ++r) {
      const long row = orow + m * 16 + r;
      const int xo = ((fk * 4 + r) & 15) << 3;
      float s = 0.f, q = 0.f;
#pragma unroll
      for (int n = 0; n < 4; ++n) {
        float v = acc[m][n][r] * 0.03125f + bi[n];
        v = v > 0.f ? v : 0.f;
        s += v;
        q += v * v;
        const int col = ocol + n * 16;
        const int phys = (col & ~127) | ((col & 127) ^ xo);
        C[row * (long)N + phys] = (unsigned char)f2e4m3(v * lw[n]);
      }
#pragma unroll
      for (int off = 1; off < 16; off <<= 1) {
        s += __shfl_xor(s, off, 64);
        q += __shfl_xor(q, off, 64);
      }
      if (fr == 0) {
        int rl = wr * 128 + m * 16 + fk * 4 + r;
        sred[rl * 4 + wc] = s;
        qred[rl * 4 + wc] = q;
      }
    }
  }
  __syncthreads();
  if (t < 256) {
    float s = sred[t * 4] + sred[t * 4 + 1] + sred[t * 4 + 2] + sred[t * 4 + 3];
    float q = qred[t * 4] + qred[t * 4 + 1] + qred[t * 4 + 2] + qred[t * 4 + 3];
    float* pb = pp + (((long)(tm * 16 + tn) * 256 + t) * 2);
    pb[0] = s;
    pb[1] = q;
  }
#undef STAGE_A
#undef STAGE_B
#undef RD_A
#undef RD_B
#undef MFMA_QUAD
}

// ============ 256x128 FP8 GEMM2, BK=128 (r16 main loop; r17: stats fused in epilogue) ============
__global__ __launch_bounds__(512, 2) void gemm256_g2(
    const unsigned char* __restrict__ A, const unsigned char* __restrict__ B,
    float* __restrict__ Cf, const float* __restrict__ bias,
    const float* __restrict__ gamma, const float* __restrict__ resid,
    const float* __restrict__ w2l, const float* __restrict__ b2l,
    const float* __restrict__ pp,
    int M, int N, int K) {
  extern __shared__ char smem[];
  const int NT = K >> 7;

  const int nwg = gridDim.x;
  const int cpx = nwg >> 3;
  const int bid = blockIdx.x;
  const int swz = (bid & 7) * cpx + (bid >> 3);
  const int tiles_m = M >> 8;
  const int tm = swz % tiles_m;
  const int tn = swz / tiles_m;
  const long brow = (long)tm * 256;
  const long bcol = (long)tn * 128;

  const int t = threadIdx.x;
  const int lane = t & 63, wv = t >> 6;
  const int wr = wv >> 1, wc = wv & 1;
  const int fr = lane & 15, fk = lane >> 4;

  const int srow = t >> 3;
  const int scol = (t & 7) * 16;
  const unsigned char* Asrc = A + (brow + srow) * (long)K + scol;
  const unsigned char* Bsrc = B + (bcol + srow) * (long)K + scol;
  const long hstep = (long)128 * K, lstep = (long)64 * K;

#define STAGE_A2(j, reg, h, L)                                                  \
  __builtin_amdgcn_global_load_lds(AS1(Asrc + (h)*hstep + (L)*lstep + (j)*128), \
      AS3(smem + (reg)*32768 + (h)*16384 + (L)*8192 + t * 16), 16, 0, 0)
#define STAGE_B2(j, L)                                                          \
  __builtin_amdgcn_global_load_lds(AS1(Bsrc + (L)*lstep + (j)*128),             \
      AS3(smem + 98304 + ((j)&1) * 16384 + (L)*8192 + t * 16), 16, 0, 0)

  const int xr = fr << 3;
  const char* ArdRow = smem + (wr * 64 + fr) * 128;
  const char* BrdRow = smem + 98304 + (wc * 64 + fr) * 128;
#define RD_A2(ar_, m, kk) \
  (*(const long*)(ArdRow + (ar_)*32768 + (m)*2048 + (((kk)*32 + fk * 8) ^ xr)))
#define RD_B2(pb_, n, kk) \
  (*(const long*)(BrdRow + (pb_)*16384 + (n)*2048 + (((kk)*32 + fk * 8) ^ xr)))

  f32x4 acc[4][4];
#pragma unroll
  for (int m = 0; m < 4; m++)
#pragma unroll
    for (int n = 0; n < 4; n++) acc[m][n] = (f32x4)0.f;

  STAGE_A2(0, 0, 0, 0); STAGE_A2(0, 0, 0, 1); STAGE_A2(0, 0, 1, 0); STAGE_A2(0, 0, 1, 1);
  STAGE_B2(0, 0); STAGE_B2(0, 1);
  STAGE_A2(1, 1, 0, 0); STAGE_A2(1, 1, 0, 1); STAGE_A2(1, 1, 1, 0); STAGE_A2(1, 1, 1, 1);
  STAGE_B2(1, 0); STAGE_B2(1, 1);
  asm volatile("s_waitcnt vmcnt(6)" ::: "memory");
  __builtin_amdgcn_s_barrier();

  long bfr[4][4];
  long ap[2][4];
  ap[0][0] = RD_A2(0, 0, 0); ap[0][1] = RD_A2(0, 0, 1);
  ap[0][2] = RD_A2(0, 0, 2); ap[0][3] = RD_A2(0, 0, 3);

  int ar = 0;
  for (int g = 0; g < NT; ++g) {
    const int pb = g & 1;
    int sr = ar + 2; if (sr >= 3) sr -= 3;
    int nar = ar + 1; if (nar >= 3) nar = 0;
    const bool st = (g + 2 < NT);
#pragma unroll
    for (int p = 0; p < 4; ++p) {
      const int cs = p & 1, ns = cs ^ 1;
      if (p == 0) {
#pragma unroll
        for (int n = 0; n < 4; ++n)
#pragma unroll
          for (int kk = 0; kk < 4; ++kk) bfr[n][kk] = RD_B2(pb, n, kk);
      }
      asm volatile("s_waitcnt lgkmcnt(0)" ::: "memory");
      __builtin_amdgcn_sched_barrier(0);
      __builtin_amdgcn_s_setprio(1);
#pragma unroll
      for (int n = 0; n < 4; ++n)
#pragma unroll
        for (int kk = 0; kk < 4; ++kk)
          acc[p][n] = __builtin_amdgcn_mfma_f32_16x16x32_fp8_fp8(
              ap[cs][kk], bfr[n][kk], acc[p][n], 0, 0, 0);
      __builtin_amdgcn_s_setprio(0);
      if (p < 3) {
#pragma unroll
        for (int kk = 0; kk < 4; ++kk) ap[ns][kk] = RD_A2(ar, p + 1, kk);
      } else if (g + 1 < NT) {
#pragma unroll
        for (int kk = 0; kk < 4; ++kk) ap[ns][kk] = RD_A2(nar, 0, kk);
      }
      if (st) {
        if (p == 0) { STAGE_A2(g + 2, sr, 0, 0); STAGE_A2(g + 2, sr, 0, 1); }
        if (p == 1) { STAGE_A2(g + 2, sr, 1, 0); STAGE_A2(g + 2, sr, 1, 1); }
        if (p == 2) { STAGE_B2(g + 2, 0); STAGE_B2(g + 2, 1); }
      }
      if (p == 2 && g + 1 < NT) {
        if (st) asm volatile("s_waitcnt vmcnt(6)" ::: "memory");
        else    asm volatile("s_waitcnt vmcnt(0)" ::: "memory");
      }
      asm volatile("s_barrier" ::: "memory");
    }
    ar = nar;
  }

  // ---- r17: row stats computed here (LDS dead after final barrier) ----
  float* stats = (float*)smem;  // [256][2]
  if (t < 256) {
    float s = 0.f, q = 0.f;
#pragma unroll
    for (int tb = 0; tb < 16; ++tb) {
      const float* p = pp + (((long)(tm * 16 + tb) * 256 + t) * 2);
      s += p[0];
      q += p[1];
    }
    float mu = s * (1.f / 4096.f);
    float var = q * (1.f / 4096.f) - mu * mu;
    stats[t * 2] = mu;
    stats[t * 2 + 1] = rsqrtf(var + 1e-6f);
  }
  __syncthreads();

  float bi[4], ga[4], wl[4], bl[4];
#pragma unroll
  for (int n = 0; n < 4; ++n) {
    const long col = bcol + wc * 64 + n * 16 + fr;
    bi[n] = bias[col];
    ga[n] = gamma[col];
    wl[n] = w2l[col];
    bl[n] = b2l[col];
  }
  const long orow = brow + wr * 64 + fk * 4;
  const long ocol = bcol + wc * 64 + fr;
  const int rl0 = wr * 64 + fk * 4;
#pragma unroll
  for (int m = 0; m < 4; ++m)
#pragma unroll
    for (int r = 0; r < 4; ++r) {
      const long row = orow + m * 16 + r;
      const int rl = rl0 + m * 16 + r;
      const float mu = stats[rl * 2];
      const float rs = stats[rl * 2 + 1];
#pragma unroll
      for (int n = 0; n < 4; ++n) {
        const long col = ocol + n * 16;
        float v = rs * (acc[m][n][r] * 0.03125f) - rs * mu * wl[n] + bl[n] + bi[n];
        Cf[row * (long)N + col] = v * ga[n] + resid[row * (long)N + col];
      }
    }
#undef STAGE_A2
#undef STAGE_B2
#undef RD_A2
#undef RD_B2
}

extern "C" void kernel_launch(void* const* d_in, const int* in_sizes, int n_in,
                              void* d_out, int out_size, void* d_ws, size_t ws_size,
                              hipStream_t stream) {
  const float* x     = (const float*)d_in[0];
  const float* W1    = (const float*)d_in[1];
  const float* b1    = (const float*)d_in[2];
  const float* ln_w  = (const float*)d_in[3];
  const float* ln_b  = (const float*)d_in[4];
  const float* W2    = (const float*)d_in[5];
  const float* b2    = (const float*)d_in[6];
  const float* gamma = (const float*)d_in[7];
  float* out = (float*)d_out;

  const int Nr = 8192, DIM = 1024, DFF = 4096, K1 = 3072;

  unsigned char* W1q   = (unsigned char*)d_ws;
  unsigned char* W2q   = W1q + (long)DFF * K1;
  unsigned char* h_in  = W2q + (long)DIM * DFF;
  unsigned char* h_act = h_in + (long)Nr * K1;
  float* partial = (float*)(h_act + (long)Nr * DFF);
  float* pp      = partial + 128 * 1024;
  float* w2l     = pp + 32 * 16 * 256 * 2;
  float* b2l     = w2l + DIM;

  hipFuncSetAttribute((const void*)gemm256_relu,
                      hipFuncAttributeMaxDynamicSharedMemorySize, 163840);
  hipFuncSetAttribute((const void*)gemm256_g2,
                      hipFuncAttributeMaxDynamicSharedMemorySize, 131072);

  // 1. fused prep: W1/W2 fp8 casts + chunkmax + w2_fold
  prep<<<3584, 256, 0, stream>>>(W1, W1q, W2, W2q, x, partial, ln_w, ln_b, w2l, b2l);

  // 2. scan_emit with inline chunk prefix/suffix
  scan_emit<<<dim3(4, 128), 256, 0, stream>>>(x, partial, h_in);

  // 3. GEMM1 (fp8 BK=128): h' = relu(h_in @ W1q^T / 32 + b1)*lnw -> fp8, + LN stats
  gemm256_relu<<<512, 512, 163840, stream>>>(h_in, W1q, h_act, b1, ln_w, pp,
                                             Nr, DFF, K1);

  // 4. GEMM2 (fp8 BK=128, stats fused): out = (...)*gamma + x
  gemm256_g2<<<256, 512, 131072, stream>>>(h_act, W2q, out, b2, gamma, x,
                                           w2l, b2l, pp, Nr, DIM, DFF);
}